// Round 2
// baseline (2391.449 us; speedup 1.0000x reference)
//
#include <hip/hip_runtime.h>
#include <math.h>

#define E_DIM 1024
#define HH 8
#define DH 128
#define BB 32
#define MM 1024
#define NTOK 32768
#define CHUNK 16384
#define CELU_A 1.3f
#define GN_EPS 1e-5f
#define SCALE_F 0.08838834764831845f   // 1/sqrt(128)

typedef unsigned short ushort_t;
typedef __attribute__((ext_vector_type(8))) short short8;
typedef __attribute__((ext_vector_type(4))) float f32x4;

#define MFMA16(a,b,c) __builtin_amdgcn_mfma_f32_16x16x32_bf16((a),(b),(c),0,0,0)

union U8 { short8 v; ushort_t u[8]; };

__device__ __forceinline__ ushort_t f2bf(float f) {
    unsigned u = __float_as_uint(f);
    u += 0x7fffu + ((u >> 16) & 1u);          // round-to-nearest-even
    return (ushort_t)(u >> 16);
}
__device__ __forceinline__ float bf2f(ushort_t h) {
    return __uint_as_float(((unsigned)h) << 16);
}

// async global -> LDS, 16B per lane (wave-linear LDS destination)
__device__ __forceinline__ void gload16(const void* g, void* l) {
    __builtin_amdgcn_global_load_lds(
        (const __attribute__((address_space(1))) unsigned*)g,
        (__attribute__((address_space(3))) unsigned*)l, 16, 0, 0);
}

// ---------------------------------------------------------------------------
// fp32 -> (hi, lo) bf16 planes. Memory-bound, 32B read / 32B write per thread.
// ---------------------------------------------------------------------------
__global__ __launch_bounds__(256)
void split_kernel(const float* __restrict__ in, ushort_t* __restrict__ hi,
                  ushort_t* __restrict__ lo, int n8)
{
    int i = blockIdx.x * 256 + threadIdx.x;
    if (i >= n8) return;
    const float4* p = (const float4*)in;
    float4 a = p[2 * i], b = p[2 * i + 1];
    float f[8] = {a.x, a.y, a.z, a.w, b.x, b.y, b.z, b.w};
    U8 h, l;
#pragma unroll
    for (int j = 0; j < 8; ++j) {
        ushort_t hh = f2bf(f[j]);
        h.u[j] = hh;
        l.u[j] = f2bf(f[j] - bf2f(hh));
    }
    *(short8*)&hi[(size_t)i * 8] = h.v;
    *(short8*)&lo[(size_t)i * 8] = l.v;
}

// ---------------------------------------------------------------------------
// Pure split-bf16 MFMA GEMM (inputs pre-split), C tile 128x128, 4 waves 2x2.
// C = X @ W^T via 3-term split: Xhi*Whi + Xhi*Wlo + Xlo*Whi.
// Staging: global_load_lds dwordx4 into linear [128][32] bf16 LDS tiles
// (64B row stride -> conflict-benign fragment reads, m97 pattern).
// MODE 0: epilogue bias+CELU+GroupNorm, write split rows [hi128|lo128]
//         into [B,H,M,256] (q or k buffer). h = blockIdx.y.
// MODE 1: same epilogue, write split TRANSPOSED into vhi/vlo [B,H,D,M].
// MODE 2: A is attn output already split in qsp layout [B,H,M,256];
//         epilogue bias only, write fp32 token-major [N,E].
// row_off: token offset of this launch's A chunk (A planes are chunk-local).
// ---------------------------------------------------------------------------
struct alignas(16) TilesT {
    ushort_t ahi[128 * 32]; ushort_t alo[128 * 32];
    ushort_t bhi[128 * 32]; ushort_t blo[128 * 32];
};
struct alignas(16) EpiT {
    float ybuf[128 * 132]; float mu[128]; float rs[128];
};
union SmemU { TilesT t; EpiT e; };

template<int MODE>
__global__ __launch_bounds__(256, 2)
void proj_kernel(const ushort_t* __restrict__ Ahi, const ushort_t* __restrict__ Alo,
                 const ushort_t* __restrict__ Bhi, const ushort_t* __restrict__ Blo,
                 const float* __restrict__ bias, const float* __restrict__ gamma,
                 const float* __restrict__ beta, int row_off,
                 ushort_t* __restrict__ out0, ushort_t* __restrict__ out1,
                 float* __restrict__ outf)
{
    __shared__ SmemU sm;

    const int tid  = threadIdx.x;
    const int w    = tid >> 6, lane = tid & 63;
    const int quad = lane >> 4, l16 = lane & 15;
    const int wr   = (w >> 1) * 64, wc = (w & 1) * 64;
    const int lrow0 = blockIdx.x * 128;        // row in (chunk-local) A planes
    const int row0  = row_off + lrow0;         // global token row (outputs)
    const int col0  = blockIdx.y * 128;

    f32x4 Cf[4][4];
#pragma unroll
    for (int i = 0; i < 4; ++i)
#pragma unroll
        for (int j = 0; j < 4; ++j) Cf[i][j] = (f32x4){0.f, 0.f, 0.f, 0.f};

    // staging slots: 512 x 16B per 8KB tile; thread owns slots s0 and s1
    const int s0 = tid, s1 = tid + 256;
    const int ra0 = tid >> 2, ra1 = ra0 + 64;  // tile rows (4 x 16B segs per row)
    const int ga  = (tid & 3) * 8;             // element offset of 16B seg

    unsigned aoff0 = 0, aoff1 = 0;
    size_t a2b0 = 0, a2b1 = 0;
    if constexpr (MODE == 2) {
        int n0 = row0 + ra0, n1 = row0 + ra1;
        a2b0 = ((size_t)(n0 >> 10) * (HH * MM) + (n0 & 1023)) * 256;
        a2b1 = ((size_t)(n1 >> 10) * (HH * MM) + (n1 & 1023)) * 256;
    } else {
        aoff0 = (unsigned)((lrow0 + ra0) * E_DIM + ga);
        aoff1 = (unsigned)((lrow0 + ra1) * E_DIM + ga);
    }
    const unsigned boff0 = (unsigned)((col0 + ra0) * E_DIM + ga);
    const unsigned boff1 = (unsigned)((col0 + ra1) * E_DIM + ga);

    for (int k0 = 0; k0 < E_DIM; k0 += 32) {
        // ---- stage A ----
        if constexpr (MODE == 2) {
            int e0 = k0 + ga;
            size_t ao = (size_t)(e0 >> 7) * (MM * 256) + (e0 & 127);
            gload16(Ahi + a2b0 + ao,       &sm.t.ahi[s0 * 8]);
            gload16(Ahi + a2b0 + ao + 128, &sm.t.alo[s0 * 8]);
            gload16(Ahi + a2b1 + ao,       &sm.t.ahi[s1 * 8]);
            gload16(Ahi + a2b1 + ao + 128, &sm.t.alo[s1 * 8]);
        } else {
            gload16(Ahi + aoff0 + k0, &sm.t.ahi[s0 * 8]);
            gload16(Alo + aoff0 + k0, &sm.t.alo[s0 * 8]);
            gload16(Ahi + aoff1 + k0, &sm.t.ahi[s1 * 8]);
            gload16(Alo + aoff1 + k0, &sm.t.alo[s1 * 8]);
        }
        // ---- stage B ----
        gload16(Bhi + boff0 + k0, &sm.t.bhi[s0 * 8]);
        gload16(Blo + boff0 + k0, &sm.t.blo[s0 * 8]);
        gload16(Bhi + boff1 + k0, &sm.t.bhi[s1 * 8]);
        gload16(Blo + boff1 + k0, &sm.t.blo[s1 * 8]);
        __syncthreads();   // drains vmcnt(0): tiles resident
        // ---- compute: 16 frag loads, 48 MFMAs ----
        short8 a_hi[4], a_lo[4], b_hi[4], b_lo[4];
#pragma unroll
        for (int mt = 0; mt < 4; ++mt) {
            int r = wr + mt * 16 + l16;
            a_hi[mt] = *(const short8*)&sm.t.ahi[r * 32 + quad * 8];
            a_lo[mt] = *(const short8*)&sm.t.alo[r * 32 + quad * 8];
        }
#pragma unroll
        for (int nt = 0; nt < 4; ++nt) {
            int r = wc + nt * 16 + l16;
            b_hi[nt] = *(const short8*)&sm.t.bhi[r * 32 + quad * 8];
            b_lo[nt] = *(const short8*)&sm.t.blo[r * 32 + quad * 8];
        }
#pragma unroll
        for (int mt = 0; mt < 4; ++mt)
#pragma unroll
            for (int nt = 0; nt < 4; ++nt) {
                f32x4 c = Cf[mt][nt];
                c = MFMA16(a_hi[mt], b_hi[nt], c);
                c = MFMA16(a_hi[mt], b_lo[nt], c);
                c = MFMA16(a_lo[mt], b_hi[nt], c);
                Cf[mt][nt] = c;
            }
        __syncthreads();
    }

    // ---- epilogue ----
    if constexpr (MODE == 2) {
#pragma unroll
        for (int mt = 0; mt < 4; ++mt)
#pragma unroll
            for (int nt = 0; nt < 4; ++nt) {
                int c = col0 + wc + nt * 16 + l16;
                float bv = bias[c];
#pragma unroll
                for (int reg = 0; reg < 4; ++reg) {
                    int r = row0 + wr + mt * 16 + quad * 4 + reg;
                    outf[(size_t)r * E_DIM + c] = Cf[mt][nt][reg] + bv;
                }
            }
    } else {
        __syncthreads();   // tiles dead; reuse LDS as ybuf
#pragma unroll
        for (int mt = 0; mt < 4; ++mt)
#pragma unroll
            for (int nt = 0; nt < 4; ++nt) {
                int c = wc + nt * 16 + l16;
                float bv = bias[col0 + c];
#pragma unroll
                for (int reg = 0; reg < 4; ++reg) {
                    int r = wr + mt * 16 + quad * 4 + reg;
                    float x = Cf[mt][nt][reg] + bv;
                    x = x > 0.f ? x : CELU_A * (__expf(x * (1.0f / CELU_A)) - 1.0f);
                    sm.e.ybuf[r * 132 + c] = x;
                }
            }
        __syncthreads();
        {   // GroupNorm stats: 2 threads/row, shfl combine
            int r = tid >> 1, off = (tid & 1) * 64;
            float s = 0.f, ss = 0.f;
            for (int i = 0; i < 64; i += 4) {
                float4 v = *(float4*)&sm.e.ybuf[r * 132 + off + i];
                s  += v.x + v.y + v.z + v.w;
                ss += v.x * v.x + v.y * v.y + v.z * v.z + v.w * v.w;
            }
            s  += __shfl_xor(s, 1);
            ss += __shfl_xor(ss, 1);
            float mu  = s * (1.f / 128.f);
            float var = ss * (1.f / 128.f) - mu * mu;
            sm.e.mu[r] = mu;
            sm.e.rs[r] = rsqrtf(var + GN_EPS);
        }
        __syncthreads();
        if constexpr (MODE == 0) {
            int r = tid >> 1, off = (tid & 1) * 64;
            int n = row0 + r, b = n >> 10, m = n & 1023, h = blockIdx.y;
            float mu = sm.e.mu[r], rs = sm.e.rs[r];
            ushort_t* orow = out0 + ((size_t)((b * HH + h) * MM + m)) * 256;
            for (int i0 = 0; i0 < 64; i0 += 8) {
                U8 ph, pl;
#pragma unroll
                for (int j = 0; j < 8; ++j) {
                    int c = off + i0 + j;
                    float y = (sm.e.ybuf[r * 132 + c] - mu) * rs * gamma[col0 + c] + beta[col0 + c];
                    ushort_t hh = f2bf(y);
                    ph.u[j] = hh; pl.u[j] = f2bf(y - bf2f(hh));
                }
                *(short8*)&orow[off + i0]       = ph.v;
                *(short8*)&orow[128 + off + i0] = pl.v;
            }
        } else {  // MODE 1: transposed V write
            int d = tid >> 1, off = (tid & 1) * 64;
            int b = row0 >> 10, m0 = row0 & 1023, h = blockIdx.y;
            float g = gamma[col0 + d], be = beta[col0 + d];
            size_t vbase = ((size_t)(b * HH + h) * DH + d) * MM + m0 + off;
            for (int i0 = 0; i0 < 64; i0 += 8) {
                U8 ph, pl;
#pragma unroll
                for (int j = 0; j < 8; ++j) {
                    int rl = off + i0 + j;
                    float y = (sm.e.ybuf[rl * 132 + d] - sm.e.mu[rl]) * sm.e.rs[rl] * g + be;
                    ushort_t hh = f2bf(y);
                    ph.u[j] = hh; pl.u[j] = f2bf(y - bf2f(hh));
                }
                *(short8*)&out0[vbase + i0] = ph.v;
                *(short8*)&out1[vbase + i0] = pl.v;
            }
        }
    }
}

// ---------------------------------------------------------------------------
// Flash attention, MFMA. Block = (b,h) x 64 Q rows, 4 waves (16 rows each).
// Q frags register-resident (split). K tiles 32 rows, V^T tiles from global.
// S = 3-term split QK^T; softmax via shfl quad-reduce; PV = 3-term split.
// O is written as SPLIT bf16 [hi128|lo128] back over this block's q rows,
// so the output projection can consume it with no conversion.
// ---------------------------------------------------------------------------
__global__ __launch_bounds__(256, 2)
void attn_kernel(const ushort_t* __restrict__ qsp, const ushort_t* __restrict__ ksp,
                 const ushort_t* __restrict__ vhi_g, const ushort_t* __restrict__ vlo_g,
                 const int* __restrict__ mask, ushort_t* __restrict__ obuf)
{
    __shared__ __align__(16) ushort_t Ks_hi[32 * 136], Ks_lo[32 * 136];
    __shared__ __align__(16) ushort_t Vt_hi[128 * 40], Vt_lo[128 * 40];
    __shared__ float Ss[64 * 33];
    __shared__ __align__(16) ushort_t Phi_s[64 * 40], Plo_s[64 * 40];
    __shared__ __align__(16) int mask_s[1024];
    __shared__ float alpha_s[64], mrow[64], lrow[64];

    const int tid  = threadIdx.x;
    const int w    = tid >> 6, lane = tid & 63;
    const int quad = lane >> 4, l16 = lane & 15;
    const int q0 = blockIdx.x * 64, bh = blockIdx.y, b = bh >> 3;

    ((int4*)mask_s)[tid] = ((const int4*)(mask + (size_t)b * MM))[tid];
    if (tid < 64) { mrow[tid] = -3.0e38f; lrow[tid] = 0.f; }

    short8 qa_hi[4], qa_lo[4];
    {
        const ushort_t* qrow = qsp + ((size_t)bh * MM + q0 + w * 16 + l16) * 256;
#pragma unroll
        for (int kc = 0; kc < 4; ++kc) {
            qa_hi[kc] = *(const short8*)(qrow + kc * 32 + quad * 8);
            qa_lo[kc] = *(const short8*)(qrow + 128 + kc * 32 + quad * 8);
        }
    }
    f32x4 Of[8];
#pragma unroll
    for (int i = 0; i < 8; ++i) Of[i] = (f32x4){0.f, 0.f, 0.f, 0.f};
    __syncthreads();

    for (int kt = 0; kt < 32; ++kt) {
        // ---- stage K tile ----
        {
            int j = tid >> 3, seg = tid & 7;
            const ushort_t* kr = ksp + ((size_t)bh * MM + kt * 32 + j) * 256 + seg * 16;
            short8 h0 = *(const short8*)(kr);
            short8 h1 = *(const short8*)(kr + 8);
            short8 l0 = *(const short8*)(kr + 128);
            short8 l1 = *(const short8*)(kr + 136);
            *(short8*)&Ks_hi[j * 136 + seg * 16 + 0] = h0;
            *(short8*)&Ks_hi[j * 136 + seg * 16 + 8] = h1;
            *(short8*)&Ks_lo[j * 136 + seg * 16 + 0] = l0;
            *(short8*)&Ks_lo[j * 136 + seg * 16 + 8] = l1;
        }
        // ---- stage V^T tile ----
        {
            int d = tid >> 1, hf = tid & 1;
            size_t vb = ((size_t)bh * DH + d) * MM + kt * 32 + hf * 16;
            short8 v0 = *(const short8*)(vhi_g + vb);
            short8 v1 = *(const short8*)(vhi_g + vb + 8);
            short8 u0 = *(const short8*)(vlo_g + vb);
            short8 u1 = *(const short8*)(vlo_g + vb + 8);
            *(short8*)&Vt_hi[d * 40 + hf * 16 + 0] = v0;
            *(short8*)&Vt_hi[d * 40 + hf * 16 + 8] = v1;
            *(short8*)&Vt_lo[d * 40 + hf * 16 + 0] = u0;
            *(short8*)&Vt_lo[d * 40 + hf * 16 + 8] = u1;
        }
        __syncthreads();
        // ---- S = split QK^T ----
        f32x4 Sf[2];
        Sf[0] = (f32x4){0.f, 0.f, 0.f, 0.f};
        Sf[1] = (f32x4){0.f, 0.f, 0.f, 0.f};
#pragma unroll
        for (int kc = 0; kc < 4; ++kc) {
#pragma unroll
            for (int ct = 0; ct < 2; ++ct) {
                const short8 kbh = *(const short8*)&Ks_hi[(ct * 16 + l16) * 136 + kc * 32 + quad * 8];
                const short8 kbl = *(const short8*)&Ks_lo[(ct * 16 + l16) * 136 + kc * 32 + quad * 8];
                f32x4 c = Sf[ct];
                c = MFMA16(qa_hi[kc], kbh, c);
                c = MFMA16(qa_hi[kc], kbl, c);
                c = MFMA16(qa_lo[kc], kbh, c);
                Sf[ct] = c;
            }
        }
#pragma unroll
        for (int ct = 0; ct < 2; ++ct)
#pragma unroll
            for (int reg = 0; reg < 4; ++reg)
                Ss[(w * 16 + quad * 4 + reg) * 33 + ct * 16 + l16] = Sf[ct][reg];
        __syncthreads();
        // ---- online softmax (all 256 threads; 4 threads/row) ----
        {
            int r = tid >> 2, cb = (tid & 3) * 8;
            float sv[8];
            float pm = -3.0e38f;
#pragma unroll
            for (int c = 0; c < 8; ++c) {
                float s = Ss[r * 33 + cb + c] * SCALE_F;
                if (mask_s[kt * 32 + cb + c] == 0) s = -1e9f;
                sv[c] = s;
                pm = fmaxf(pm, s);
            }
            pm = fmaxf(pm, __shfl_xor(pm, 1));
            pm = fmaxf(pm, __shfl_xor(pm, 2));
            float mo = mrow[r];
            float mx = fmaxf(mo, pm);
            float al = __expf(mo - mx);
            float ps = 0.f;
            U8 ph, pl;
#pragma unroll
            for (int c = 0; c < 8; ++c) {
                float p = __expf(sv[c] - mx);
                ps += p;
                ushort_t hh = f2bf(p);
                ph.u[c] = hh;
                pl.u[c] = f2bf(p - bf2f(hh));
            }
            *(short8*)&Phi_s[r * 40 + cb] = ph.v;
            *(short8*)&Plo_s[r * 40 + cb] = pl.v;
            ps += __shfl_xor(ps, 1);
            ps += __shfl_xor(ps, 2);
            if ((tid & 3) == 0) {
                mrow[r] = mx;
                alpha_s[r] = al;
                lrow[r] = lrow[r] * al + ps;
            }
        }
        __syncthreads();
        // ---- O = O*alpha + split P@V ----
        {
            float ar[4];
#pragma unroll
            for (int reg = 0; reg < 4; ++reg) ar[reg] = alpha_s[w * 16 + quad * 4 + reg];
            const short8 pah = *(const short8*)&Phi_s[(w * 16 + l16) * 40 + quad * 8];
            const short8 pal = *(const short8*)&Plo_s[(w * 16 + l16) * 40 + quad * 8];
#pragma unroll
            for (int ct = 0; ct < 8; ++ct) {
                f32x4 c = Of[ct];
#pragma unroll
                for (int reg = 0; reg < 4; ++reg) c[reg] *= ar[reg];
                const short8 vbh = *(const short8*)&Vt_hi[(ct * 16 + l16) * 40 + quad * 8];
                const short8 vbl = *(const short8*)&Vt_lo[(ct * 16 + l16) * 40 + quad * 8];
                c = MFMA16(pah, vbh, c);
                c = MFMA16(pah, vbl, c);
                c = MFMA16(pal, vbh, c);
                Of[ct] = c;
            }
        }
        __syncthreads();
    }
    // ---- epilogue: O/l -> split bf16, overwrite q rows in qsp layout ----
    {
        float li[4];
#pragma unroll
        for (int reg = 0; reg < 4; ++reg) li[reg] = 1.f / lrow[w * 16 + quad * 4 + reg];
#pragma unroll
        for (int ct = 0; ct < 8; ++ct)
#pragma unroll
            for (int reg = 0; reg < 4; ++reg) {
                float v = Of[ct][reg] * li[reg];
                ushort_t hh = f2bf(v);
                ushort_t ll = f2bf(v - bf2f(hh));
                size_t rb = ((size_t)bh * MM + q0 + w * 16 + quad * 4 + reg) * 256 + ct * 16 + l16;
                obuf[rb]       = hh;
                obuf[rb + 128] = ll;
            }
    }
}

// ---------------------------------------------------------------------------
// Launch schedule / workspace choreography (ws = 384MB, unchanged layout):
//   qsp [134MB] | ksp [134MB] | vhi [67MB] | vlo [67MB]
// d_out (134MB) doubles as X-split scratch until the final projection.
// Per-proj X is split in 2 chunks of 16384 rows (67MB scratch) so the third
// projection fits while qsp/vhi/vlo are live. W splits (4MB) live in regions
// dead at their use time:
//   Wv -> qsp region   (dead until projq writes qsp)
//   Wq -> ksp region   (dead until projk writes ksp)
//   Wk -> d_out+64MB   (beyond chunk scratch; dead until projm writes d_out)
//   Wm -> ksp region   (split after attn; ksp dead then)
// ---------------------------------------------------------------------------
extern "C" void kernel_launch(void* const* d_in, const int* in_sizes, int n_in,
                              void* d_out, int out_size, void* d_ws, size_t ws_size,
                              hipStream_t stream)
{
    const float* query  = (const float*)d_in[0];
    const float* key    = (const float*)d_in[1];
    const int*   mask   = (const int*)d_in[2];
    // d_in[3] = value1 (unused by reference)
    const float* value2 = (const float*)d_in[4];
    const float* Wq = (const float*)d_in[5];
    const float* bq = (const float*)d_in[6];
    const float* gq = (const float*)d_in[7];
    const float* betaq = (const float*)d_in[8];
    const float* Wk = (const float*)d_in[9];
    const float* bk = (const float*)d_in[10];
    const float* gk = (const float*)d_in[11];
    const float* betak = (const float*)d_in[12];
    const float* Wv = (const float*)d_in[13];
    const float* bv = (const float*)d_in[14];
    const float* gv = (const float*)d_in[15];
    const float* betav = (const float*)d_in[16];
    const float* Wm = (const float*)d_in[17];
    const float* bm = (const float*)d_in[18];
    float* out = (float*)d_out;

    ushort_t* qsp = (ushort_t*)d_ws;                       // [B,H,M, hi128|lo128]
    ushort_t* ksp = qsp + (size_t)67108864;
    ushort_t* vhi = ksp + (size_t)67108864;                // [B,H,D,M]
    ushort_t* vlo = vhi + (size_t)33554432;

    ushort_t* ob   = (ushort_t*)d_out;
    ushort_t* xhi  = ob;                                   // chunk X scratch (33.5MB)
    ushort_t* xlo  = ob + (size_t)CHUNK * E_DIM;           // +33.5MB
    ushort_t* wkhi = ob + (size_t)2 * CHUNK * E_DIM;       // Wk split @ d_out+64MB(elems)
    ushort_t* wklo = wkhi + (size_t)E_DIM * E_DIM;
    ushort_t* wvhi = qsp;                                  // Wv split in qsp region
    ushort_t* wvlo = wvhi + (size_t)E_DIM * E_DIM;
    ushort_t* wqhi = ksp;                                  // Wq split in ksp region
    ushort_t* wqlo = wqhi + (size_t)E_DIM * E_DIM;
    ushort_t* wmhi = ksp;                                  // Wm split (after attn)
    ushort_t* wmlo = wmhi + (size_t)E_DIM * E_DIM;

    const int WN8 = (E_DIM * E_DIM) / 8;       // 131072
    const int XN8 = (CHUNK * E_DIM) / 8;       // 2097152

    split_kernel<<<WN8 / 256, 256, 0, stream>>>(Wv, wvhi, wvlo, WN8);
    split_kernel<<<WN8 / 256, 256, 0, stream>>>(Wq, wqhi, wqlo, WN8);
    split_kernel<<<WN8 / 256, 256, 0, stream>>>(Wk, wkhi, wklo, WN8);

    dim3 gproj(CHUNK / 128, E_DIM / 128);      // (128, 8)

    for (int c = 0; c < 2; ++c) {
        split_kernel<<<XN8 / 256, 256, 0, stream>>>(value2 + (size_t)c * CHUNK * E_DIM, xhi, xlo, XN8);
        proj_kernel<1><<<gproj, 256, 0, stream>>>(xhi, xlo, wvhi, wvlo, bv, gv, betav,
                                                  c * CHUNK, vhi, vlo, nullptr);
    }
    for (int c = 0; c < 2; ++c) {
        split_kernel<<<XN8 / 256, 256, 0, stream>>>(query + (size_t)c * CHUNK * E_DIM, xhi, xlo, XN8);
        proj_kernel<0><<<gproj, 256, 0, stream>>>(xhi, xlo, wqhi, wqlo, bq, gq, betaq,
                                                  c * CHUNK, qsp, nullptr, nullptr);
    }
    for (int c = 0; c < 2; ++c) {
        split_kernel<<<XN8 / 256, 256, 0, stream>>>(key + (size_t)c * CHUNK * E_DIM, xhi, xlo, XN8);
        proj_kernel<0><<<gproj, 256, 0, stream>>>(xhi, xlo, wkhi, wklo, bk, gk, betak,
                                                  c * CHUNK, ksp, nullptr, nullptr);
    }

    attn_kernel<<<dim3(MM / 64, BB * HH), 256, 0, stream>>>(qsp, ksp, vhi, vlo, mask, qsp);

    split_kernel<<<WN8 / 256, 256, 0, stream>>>(Wm, wmhi, wmlo, WN8);
    proj_kernel<2><<<dim3(NTOK / 128, E_DIM / 128), 256, 0, stream>>>(
        qsp, nullptr, wmhi, wmlo, bm, nullptr, nullptr, 0, nullptr, nullptr, out);
}

// Round 3
// 2224.493 us; speedup vs baseline: 1.0751x; 1.0751x over previous
//
#include <hip/hip_runtime.h>
#include <math.h>

#define E_DIM 1024
#define HH 8
#define DH 128
#define BB 32
#define MM 1024
#define NTOK 32768
#define CHUNK 16384
#define CELU_A 1.3f
#define GN_EPS 1e-5f
#define SCALE_F 0.08838834764831845f   // 1/sqrt(128)

typedef unsigned short ushort_t;
typedef __attribute__((ext_vector_type(8))) short short8;
typedef __attribute__((ext_vector_type(4))) float f32x4;

#define MFMA16(a,b,c) __builtin_amdgcn_mfma_f32_16x16x32_bf16((a),(b),(c),0,0,0)

union U8 { short8 v; ushort_t u[8]; };

__device__ __forceinline__ ushort_t f2bf(float f) {
    unsigned u = __float_as_uint(f);
    u += 0x7fffu + ((u >> 16) & 1u);          // round-to-nearest-even
    return (ushort_t)(u >> 16);
}
__device__ __forceinline__ float bf2f(ushort_t h) {
    return __uint_as_float(((unsigned)h) << 16);
}

// async global -> LDS, 16B per lane (wave-linear LDS destination)
__device__ __forceinline__ void gload16(const void* g, void* l) {
    __builtin_amdgcn_global_load_lds(
        (const __attribute__((address_space(1))) unsigned*)g,
        (__attribute__((address_space(3))) unsigned*)l, 16, 0, 0);
}

// ---------------------------------------------------------------------------
// fp32 -> (hi, lo) bf16 planes. Memory-bound, 32B read / 32B write per thread.
// ---------------------------------------------------------------------------
__global__ __launch_bounds__(256)
void split_kernel(const float* __restrict__ in, ushort_t* __restrict__ hi,
                  ushort_t* __restrict__ lo, int n8)
{
    int i = blockIdx.x * 256 + threadIdx.x;
    if (i >= n8) return;
    const float4* p = (const float4*)in;
    float4 a = p[2 * i], b = p[2 * i + 1];
    float f[8] = {a.x, a.y, a.z, a.w, b.x, b.y, b.z, b.w};
    U8 h, l;
#pragma unroll
    for (int j = 0; j < 8; ++j) {
        ushort_t hh = f2bf(f[j]);
        h.u[j] = hh;
        l.u[j] = f2bf(f[j] - bf2f(hh));
    }
    *(short8*)&hi[(size_t)i * 8] = h.v;
    *(short8*)&lo[(size_t)i * 8] = l.v;
}

// ---------------------------------------------------------------------------
// Pure split-bf16 MFMA GEMM (inputs pre-split), C tile 128x128, 4 waves 2x2.
// C = X @ W^T via 3-term split: Xhi*Whi + Xhi*Wlo + Xlo*Whi.
// Staging: global_load_lds dwordx4 into linear [128][32] bf16 LDS tiles.
// Epilogue processes the tile in TWO 64-row halves so the LDS union stays
// ~34 KB (vs 68 KB) -> 3 blocks/CU instead of 2 (m132: the 64 KB-LDS
// occupancy cliff costs ~1.7x on this 2-barrier structure).
// MODE 0: bias+CELU+GroupNorm, write split rows [hi128|lo128] into
//         [B,H,M,256] (q or k buffer). h = blockIdx.y.
// MODE 1: same epilogue, write split TRANSPOSED into vhi/vlo [B,H,D,M].
// MODE 2: A is attn output already split in qsp layout [B,H,M,256];
//         epilogue bias only, write fp32 token-major [N,E].
// row_off: token offset of this launch's A chunk (A planes are chunk-local).
// ---------------------------------------------------------------------------
struct alignas(16) TilesT {
    ushort_t ahi[128 * 32]; ushort_t alo[128 * 32];
    ushort_t bhi[128 * 32]; ushort_t blo[128 * 32];
};
struct alignas(16) EpiT {
    float ybuf[64 * 132]; float mu[64]; float rs[64];
};
union SmemU { TilesT t; EpiT e; };

template<int MODE>
__global__ __launch_bounds__(256, 3)
void proj_kernel(const ushort_t* __restrict__ Ahi, const ushort_t* __restrict__ Alo,
                 const ushort_t* __restrict__ Bhi, const ushort_t* __restrict__ Blo,
                 const float* __restrict__ bias, const float* __restrict__ gamma,
                 const float* __restrict__ beta, int row_off,
                 ushort_t* __restrict__ out0, ushort_t* __restrict__ out1,
                 float* __restrict__ outf)
{
    __shared__ SmemU sm;

    const int tid  = threadIdx.x;
    const int w    = tid >> 6, lane = tid & 63;
    const int quad = lane >> 4, l16 = lane & 15;
    const int wr   = (w >> 1) * 64, wc = (w & 1) * 64;
    const int lrow0 = blockIdx.x * 128;        // row in (chunk-local) A planes
    const int row0  = row_off + lrow0;         // global token row (outputs)
    const int col0  = blockIdx.y * 128;

    f32x4 Cf[4][4];
#pragma unroll
    for (int i = 0; i < 4; ++i)
#pragma unroll
        for (int j = 0; j < 4; ++j) Cf[i][j] = (f32x4){0.f, 0.f, 0.f, 0.f};

    // staging slots: 512 x 16B per 8KB tile; thread owns slots s0 and s1
    const int s0 = tid, s1 = tid + 256;
    const int ra0 = tid >> 2, ra1 = ra0 + 64;  // tile rows (4 x 16B segs per row)
    const int ga  = (tid & 3) * 8;             // element offset of 16B seg

    unsigned aoff0 = 0, aoff1 = 0;
    size_t a2b0 = 0, a2b1 = 0;
    if constexpr (MODE == 2) {
        int n0 = row0 + ra0, n1 = row0 + ra1;
        a2b0 = ((size_t)(n0 >> 10) * (HH * MM) + (n0 & 1023)) * 256;
        a2b1 = ((size_t)(n1 >> 10) * (HH * MM) + (n1 & 1023)) * 256;
    } else {
        aoff0 = (unsigned)((lrow0 + ra0) * E_DIM + ga);
        aoff1 = (unsigned)((lrow0 + ra1) * E_DIM + ga);
    }
    const unsigned boff0 = (unsigned)((col0 + ra0) * E_DIM + ga);
    const unsigned boff1 = (unsigned)((col0 + ra1) * E_DIM + ga);

    for (int k0 = 0; k0 < E_DIM; k0 += 32) {
        // ---- stage A ----
        if constexpr (MODE == 2) {
            int e0 = k0 + ga;
            size_t ao = (size_t)(e0 >> 7) * (MM * 256) + (e0 & 127);
            gload16(Ahi + a2b0 + ao,       &sm.t.ahi[s0 * 8]);
            gload16(Ahi + a2b0 + ao + 128, &sm.t.alo[s0 * 8]);
            gload16(Ahi + a2b1 + ao,       &sm.t.ahi[s1 * 8]);
            gload16(Ahi + a2b1 + ao + 128, &sm.t.alo[s1 * 8]);
        } else {
            gload16(Ahi + aoff0 + k0, &sm.t.ahi[s0 * 8]);
            gload16(Alo + aoff0 + k0, &sm.t.alo[s0 * 8]);
            gload16(Ahi + aoff1 + k0, &sm.t.ahi[s1 * 8]);
            gload16(Alo + aoff1 + k0, &sm.t.alo[s1 * 8]);
        }
        // ---- stage B ----
        gload16(Bhi + boff0 + k0, &sm.t.bhi[s0 * 8]);
        gload16(Blo + boff0 + k0, &sm.t.blo[s0 * 8]);
        gload16(Bhi + boff1 + k0, &sm.t.bhi[s1 * 8]);
        gload16(Blo + boff1 + k0, &sm.t.blo[s1 * 8]);
        __syncthreads();   // drains vmcnt(0): tiles resident
        // ---- compute: 16 frag loads, 48 MFMAs ----
        short8 a_hi[4], a_lo[4], b_hi[4], b_lo[4];
#pragma unroll
        for (int mt = 0; mt < 4; ++mt) {
            int r = wr + mt * 16 + l16;
            a_hi[mt] = *(const short8*)&sm.t.ahi[r * 32 + quad * 8];
            a_lo[mt] = *(const short8*)&sm.t.alo[r * 32 + quad * 8];
        }
#pragma unroll
        for (int nt = 0; nt < 4; ++nt) {
            int r = wc + nt * 16 + l16;
            b_hi[nt] = *(const short8*)&sm.t.bhi[r * 32 + quad * 8];
            b_lo[nt] = *(const short8*)&sm.t.blo[r * 32 + quad * 8];
        }
#pragma unroll
        for (int mt = 0; mt < 4; ++mt)
#pragma unroll
            for (int nt = 0; nt < 4; ++nt) {
                f32x4 c = Cf[mt][nt];
                c = MFMA16(a_hi[mt], b_hi[nt], c);
                c = MFMA16(a_hi[mt], b_lo[nt], c);
                c = MFMA16(a_lo[mt], b_hi[nt], c);
                Cf[mt][nt] = c;
            }
        __syncthreads();
    }

    // ---- epilogue ----
    if constexpr (MODE == 2) {
#pragma unroll
        for (int mt = 0; mt < 4; ++mt)
#pragma unroll
            for (int nt = 0; nt < 4; ++nt) {
                int c = col0 + wc + nt * 16 + l16;
                float bv = bias[c];
#pragma unroll
                for (int reg = 0; reg < 4; ++reg) {
                    int r = row0 + wr + mt * 16 + quad * 4 + reg;
                    outf[(size_t)r * E_DIM + c] = Cf[mt][nt][reg] + bv;
                }
            }
    } else {
        // two 64-row halves; ybuf is [64][132] fp32 (34 KB union -> 3 blk/CU)
        for (int h2 = 0; h2 < 2; ++h2) {
            __syncthreads();   // tiles dead / previous half consumed
            if ((w >> 1) == h2) {   // the 2 waves owning these 64 rows
#pragma unroll
                for (int mt = 0; mt < 4; ++mt)
#pragma unroll
                    for (int nt = 0; nt < 4; ++nt) {
                        int c = wc + nt * 16 + l16;
                        float bv = bias[col0 + c];
#pragma unroll
                        for (int reg = 0; reg < 4; ++reg) {
                            int r = mt * 16 + quad * 4 + reg;   // 0..63 local
                            float x = Cf[mt][nt][reg] + bv;
                            x = x > 0.f ? x : CELU_A * (__expf(x * (1.0f / CELU_A)) - 1.0f);
                            sm.e.ybuf[r * 132 + c] = x;
                        }
                    }
            }
            __syncthreads();
            {   // GroupNorm stats: 4 threads/row, 32 cols each, shfl combine
                int r = tid >> 2, sg = (tid & 3) * 32;
                float s = 0.f, ss = 0.f;
                for (int i = 0; i < 32; i += 4) {
                    float4 v = *(float4*)&sm.e.ybuf[r * 132 + sg + i];
                    s  += v.x + v.y + v.z + v.w;
                    ss += v.x * v.x + v.y * v.y + v.z * v.z + v.w * v.w;
                }
                s  += __shfl_xor(s, 1);  ss += __shfl_xor(ss, 1);
                s  += __shfl_xor(s, 2);  ss += __shfl_xor(ss, 2);
                if ((tid & 3) == 0) {
                    float mu  = s * (1.f / 128.f);
                    float var = ss * (1.f / 128.f) - mu * mu;
                    sm.e.mu[r] = mu;
                    sm.e.rs[r] = rsqrtf(var + GN_EPS);
                }
            }
            __syncthreads();
            if constexpr (MODE == 0) {
                int r = tid >> 2, sg = (tid & 3) * 32;
                int n = row0 + h2 * 64 + r, b = n >> 10, m = n & 1023, h = blockIdx.y;
                float mu = sm.e.mu[r], rs = sm.e.rs[r];
                ushort_t* orow = out0 + ((size_t)((b * HH + h) * MM + m)) * 256;
                for (int i0 = 0; i0 < 32; i0 += 8) {
                    U8 ph, pl;
#pragma unroll
                    for (int j = 0; j < 8; ++j) {
                        int c = sg + i0 + j;
                        float y = (sm.e.ybuf[r * 132 + c] - mu) * rs * gamma[col0 + c] + beta[col0 + c];
                        ushort_t hh = f2bf(y);
                        ph.u[j] = hh; pl.u[j] = f2bf(y - bf2f(hh));
                    }
                    *(short8*)&orow[sg + i0]       = ph.v;
                    *(short8*)&orow[128 + sg + i0] = pl.v;
                }
            } else {  // MODE 1: transposed V write, 2 threads/col, 32 rows each
                int d = tid >> 1, off = (tid & 1) * 32;
                int b = row0 >> 10, m0 = (row0 & 1023) + h2 * 64, h = blockIdx.y;
                float g = gamma[col0 + d], be = beta[col0 + d];
                size_t vbase = ((size_t)(b * HH + h) * DH + d) * MM + m0 + off;
                for (int i0 = 0; i0 < 32; i0 += 8) {
                    U8 ph, pl;
#pragma unroll
                    for (int j = 0; j < 8; ++j) {
                        int rl = off + i0 + j;
                        float y = (sm.e.ybuf[rl * 132 + d] - sm.e.mu[rl]) * sm.e.rs[rl] * g + be;
                        ushort_t hh = f2bf(y);
                        ph.u[j] = hh; pl.u[j] = f2bf(y - bf2f(hh));
                    }
                    *(short8*)&out0[vbase + i0] = ph.v;
                    *(short8*)&out1[vbase + i0] = pl.v;
                }
            }
        }
    }
}

// ---------------------------------------------------------------------------
// Flash attention, MFMA. Block = (b,h) x 64 Q rows, 4 waves (16 rows each).
// Q frags register-resident (split). K tiles 32 rows, V^T tiles from global.
// S = 3-term split QK^T; softmax via shfl quad-reduce; PV = 3-term split.
// O is written as SPLIT bf16 [hi128|lo128] back over this block's q rows,
// so the output projection can consume it with no conversion.
// ---------------------------------------------------------------------------
__global__ __launch_bounds__(256, 2)
void attn_kernel(const ushort_t* __restrict__ qsp, const ushort_t* __restrict__ ksp,
                 const ushort_t* __restrict__ vhi_g, const ushort_t* __restrict__ vlo_g,
                 const int* __restrict__ mask, ushort_t* __restrict__ obuf)
{
    __shared__ __align__(16) ushort_t Ks_hi[32 * 136], Ks_lo[32 * 136];
    __shared__ __align__(16) ushort_t Vt_hi[128 * 40], Vt_lo[128 * 40];
    __shared__ float Ss[64 * 33];
    __shared__ __align__(16) ushort_t Phi_s[64 * 40], Plo_s[64 * 40];
    __shared__ __align__(16) int mask_s[1024];
    __shared__ float alpha_s[64], mrow[64], lrow[64];

    const int tid  = threadIdx.x;
    const int w    = tid >> 6, lane = tid & 63;
    const int quad = lane >> 4, l16 = lane & 15;
    const int q0 = blockIdx.x * 64, bh = blockIdx.y, b = bh >> 3;

    ((int4*)mask_s)[tid] = ((const int4*)(mask + (size_t)b * MM))[tid];
    if (tid < 64) { mrow[tid] = -3.0e38f; lrow[tid] = 0.f; }

    short8 qa_hi[4], qa_lo[4];
    {
        const ushort_t* qrow = qsp + ((size_t)bh * MM + q0 + w * 16 + l16) * 256;
#pragma unroll
        for (int kc = 0; kc < 4; ++kc) {
            qa_hi[kc] = *(const short8*)(qrow + kc * 32 + quad * 8);
            qa_lo[kc] = *(const short8*)(qrow + 128 + kc * 32 + quad * 8);
        }
    }
    f32x4 Of[8];
#pragma unroll
    for (int i = 0; i < 8; ++i) Of[i] = (f32x4){0.f, 0.f, 0.f, 0.f};
    __syncthreads();

    for (int kt = 0; kt < 32; ++kt) {
        // ---- stage K tile ----
        {
            int j = tid >> 3, seg = tid & 7;
            const ushort_t* kr = ksp + ((size_t)bh * MM + kt * 32 + j) * 256 + seg * 16;
            short8 h0 = *(const short8*)(kr);
            short8 h1 = *(const short8*)(kr + 8);
            short8 l0 = *(const short8*)(kr + 128);
            short8 l1 = *(const short8*)(kr + 136);
            *(short8*)&Ks_hi[j * 136 + seg * 16 + 0] = h0;
            *(short8*)&Ks_hi[j * 136 + seg * 16 + 8] = h1;
            *(short8*)&Ks_lo[j * 136 + seg * 16 + 0] = l0;
            *(short8*)&Ks_lo[j * 136 + seg * 16 + 8] = l1;
        }
        // ---- stage V^T tile ----
        {
            int d = tid >> 1, hf = tid & 1;
            size_t vb = ((size_t)bh * DH + d) * MM + kt * 32 + hf * 16;
            short8 v0 = *(const short8*)(vhi_g + vb);
            short8 v1 = *(const short8*)(vhi_g + vb + 8);
            short8 u0 = *(const short8*)(vlo_g + vb);
            short8 u1 = *(const short8*)(vlo_g + vb + 8);
            *(short8*)&Vt_hi[d * 40 + hf * 16 + 0] = v0;
            *(short8*)&Vt_hi[d * 40 + hf * 16 + 8] = v1;
            *(short8*)&Vt_lo[d * 40 + hf * 16 + 0] = u0;
            *(short8*)&Vt_lo[d * 40 + hf * 16 + 8] = u1;
        }
        __syncthreads();
        // ---- S = split QK^T ----
        f32x4 Sf[2];
        Sf[0] = (f32x4){0.f, 0.f, 0.f, 0.f};
        Sf[1] = (f32x4){0.f, 0.f, 0.f, 0.f};
#pragma unroll
        for (int kc = 0; kc < 4; ++kc) {
#pragma unroll
            for (int ct = 0; ct < 2; ++ct) {
                const short8 kbh = *(const short8*)&Ks_hi[(ct * 16 + l16) * 136 + kc * 32 + quad * 8];
                const short8 kbl = *(const short8*)&Ks_lo[(ct * 16 + l16) * 136 + kc * 32 + quad * 8];
                f32x4 c = Sf[ct];
                c = MFMA16(qa_hi[kc], kbh, c);
                c = MFMA16(qa_hi[kc], kbl, c);
                c = MFMA16(qa_lo[kc], kbh, c);
                Sf[ct] = c;
            }
        }
#pragma unroll
        for (int ct = 0; ct < 2; ++ct)
#pragma unroll
            for (int reg = 0; reg < 4; ++reg)
                Ss[(w * 16 + quad * 4 + reg) * 33 + ct * 16 + l16] = Sf[ct][reg];
        __syncthreads();
        // ---- online softmax (all 256 threads; 4 threads/row) ----
        {
            int r = tid >> 2, cb = (tid & 3) * 8;
            float sv[8];
            float pm = -3.0e38f;
#pragma unroll
            for (int c = 0; c < 8; ++c) {
                float s = Ss[r * 33 + cb + c] * SCALE_F;
                if (mask_s[kt * 32 + cb + c] == 0) s = -1e9f;
                sv[c] = s;
                pm = fmaxf(pm, s);
            }
            pm = fmaxf(pm, __shfl_xor(pm, 1));
            pm = fmaxf(pm, __shfl_xor(pm, 2));
            float mo = mrow[r];
            float mx = fmaxf(mo, pm);
            float al = __expf(mo - mx);
            float ps = 0.f;
            U8 ph, pl;
#pragma unroll
            for (int c = 0; c < 8; ++c) {
                float p = __expf(sv[c] - mx);
                ps += p;
                ushort_t hh = f2bf(p);
                ph.u[c] = hh;
                pl.u[c] = f2bf(p - bf2f(hh));
            }
            *(short8*)&Phi_s[r * 40 + cb] = ph.v;
            *(short8*)&Plo_s[r * 40 + cb] = pl.v;
            ps += __shfl_xor(ps, 1);
            ps += __shfl_xor(ps, 2);
            if ((tid & 3) == 0) {
                mrow[r] = mx;
                alpha_s[r] = al;
                lrow[r] = lrow[r] * al + ps;
            }
        }
        __syncthreads();
        // ---- O = O*alpha + split P@V ----
        {
            float ar[4];
#pragma unroll
            for (int reg = 0; reg < 4; ++reg) ar[reg] = alpha_s[w * 16 + quad * 4 + reg];
            const short8 pah = *(const short8*)&Phi_s[(w * 16 + l16) * 40 + quad * 8];
            const short8 pal = *(const short8*)&Plo_s[(w * 16 + l16) * 40 + quad * 8];
#pragma unroll
            for (int ct = 0; ct < 8; ++ct) {
                f32x4 c = Of[ct];
#pragma unroll
                for (int reg = 0; reg < 4; ++reg) c[reg] *= ar[reg];
                const short8 vbh = *(const short8*)&Vt_hi[(ct * 16 + l16) * 40 + quad * 8];
                const short8 vbl = *(const short8*)&Vt_lo[(ct * 16 + l16) * 40 + quad * 8];
                c = MFMA16(pah, vbh, c);
                c = MFMA16(pah, vbl, c);
                c = MFMA16(pal, vbh, c);
                Of[ct] = c;
            }
        }
        __syncthreads();
    }
    // ---- epilogue: O/l -> split bf16, overwrite q rows in qsp layout ----
    {
        float li[4];
#pragma unroll
        for (int reg = 0; reg < 4; ++reg) li[reg] = 1.f / lrow[w * 16 + quad * 4 + reg];
#pragma unroll
        for (int ct = 0; ct < 8; ++ct)
#pragma unroll
            for (int reg = 0; reg < 4; ++reg) {
                float v = Of[ct][reg] * li[reg];
                ushort_t hh = f2bf(v);
                ushort_t ll = f2bf(v - bf2f(hh));
                size_t rb = ((size_t)bh * MM + q0 + w * 16 + quad * 4 + reg) * 256 + ct * 16 + l16;
                obuf[rb]       = hh;
                obuf[rb + 128] = ll;
            }
    }
}

// ---------------------------------------------------------------------------
// Launch schedule / workspace choreography (ws = 384MB, unchanged layout):
//   qsp [134MB] | ksp [134MB] | vhi [67MB] | vlo [67MB]
// d_out (134MB) doubles as X-split scratch until the final projection.
// Per-proj X is split in 2 chunks of 16384 rows (67MB scratch) so the third
// projection fits while qsp/vhi/vlo are live. W splits (4MB) live in regions
// dead at their use time:
//   Wv -> qsp region   (dead until projq writes qsp)
//   Wq -> ksp region   (dead until projk writes ksp)
//   Wk -> d_out+64MB   (beyond chunk scratch; dead until projm writes d_out)
//   Wm -> ksp region   (split after attn; ksp dead then)
// ---------------------------------------------------------------------------
extern "C" void kernel_launch(void* const* d_in, const int* in_sizes, int n_in,
                              void* d_out, int out_size, void* d_ws, size_t ws_size,
                              hipStream_t stream)
{
    const float* query  = (const float*)d_in[0];
    const float* key    = (const float*)d_in[1];
    const int*   mask   = (const int*)d_in[2];
    // d_in[3] = value1 (unused by reference)
    const float* value2 = (const float*)d_in[4];
    const float* Wq = (const float*)d_in[5];
    const float* bq = (const float*)d_in[6];
    const float* gq = (const float*)d_in[7];
    const float* betaq = (const float*)d_in[8];
    const float* Wk = (const float*)d_in[9];
    const float* bk = (const float*)d_in[10];
    const float* gk = (const float*)d_in[11];
    const float* betak = (const float*)d_in[12];
    const float* Wv = (const float*)d_in[13];
    const float* bv = (const float*)d_in[14];
    const float* gv = (const float*)d_in[15];
    const float* betav = (const float*)d_in[16];
    const float* Wm = (const float*)d_in[17];
    const float* bm = (const float*)d_in[18];
    float* out = (float*)d_out;

    ushort_t* qsp = (ushort_t*)d_ws;                       // [B,H,M, hi128|lo128]
    ushort_t* ksp = qsp + (size_t)67108864;
    ushort_t* vhi = ksp + (size_t)67108864;                // [B,H,D,M]
    ushort_t* vlo = vhi + (size_t)33554432;

    ushort_t* ob   = (ushort_t*)d_out;
    ushort_t* xhi  = ob;                                   // chunk X scratch (33.5MB)
    ushort_t* xlo  = ob + (size_t)CHUNK * E_DIM;           // +33.5MB
    ushort_t* wkhi = ob + (size_t)2 * CHUNK * E_DIM;       // Wk split @ d_out+64MB(elems)
    ushort_t* wklo = wkhi + (size_t)E_DIM * E_DIM;
    ushort_t* wvhi = qsp;                                  // Wv split in qsp region
    ushort_t* wvlo = wvhi + (size_t)E_DIM * E_DIM;
    ushort_t* wqhi = ksp;                                  // Wq split in ksp region
    ushort_t* wqlo = wqhi + (size_t)E_DIM * E_DIM;
    ushort_t* wmhi = ksp;                                  // Wm split (after attn)
    ushort_t* wmlo = wmhi + (size_t)E_DIM * E_DIM;

    const int WN8 = (E_DIM * E_DIM) / 8;       // 131072
    const int XN8 = (CHUNK * E_DIM) / 8;       // 2097152

    split_kernel<<<WN8 / 256, 256, 0, stream>>>(Wv, wvhi, wvlo, WN8);
    split_kernel<<<WN8 / 256, 256, 0, stream>>>(Wq, wqhi, wqlo, WN8);
    split_kernel<<<WN8 / 256, 256, 0, stream>>>(Wk, wkhi, wklo, WN8);

    dim3 gproj(CHUNK / 128, E_DIM / 128);      // (128, 8)

    for (int c = 0; c < 2; ++c) {
        split_kernel<<<XN8 / 256, 256, 0, stream>>>(value2 + (size_t)c * CHUNK * E_DIM, xhi, xlo, XN8);
        proj_kernel<1><<<gproj, 256, 0, stream>>>(xhi, xlo, wvhi, wvlo, bv, gv, betav,
                                                  c * CHUNK, vhi, vlo, nullptr);
    }
    for (int c = 0; c < 2; ++c) {
        split_kernel<<<XN8 / 256, 256, 0, stream>>>(query + (size_t)c * CHUNK * E_DIM, xhi, xlo, XN8);
        proj_kernel<0><<<gproj, 256, 0, stream>>>(xhi, xlo, wqhi, wqlo, bq, gq, betaq,
                                                  c * CHUNK, qsp, nullptr, nullptr);
    }
    for (int c = 0; c < 2; ++c) {
        split_kernel<<<XN8 / 256, 256, 0, stream>>>(key + (size_t)c * CHUNK * E_DIM, xhi, xlo, XN8);
        proj_kernel<0><<<gproj, 256, 0, stream>>>(xhi, xlo, wkhi, wklo, bk, gk, betak,
                                                  c * CHUNK, ksp, nullptr, nullptr);
    }

    attn_kernel<<<dim3(MM / 64, BB * HH), 256, 0, stream>>>(qsp, ksp, vhi, vlo, mask, qsp);

    split_kernel<<<WN8 / 256, 256, 0, stream>>>(Wm, wmhi, wmlo, WN8);
    proj_kernel<2><<<dim3(NTOK / 128, E_DIM / 128), 256, 0, stream>>>(
        qsp, nullptr, wmhi, wmlo, bm, nullptr, nullptr, 0, nullptr, nullptr, out);
}

// Round 4
// 2190.029 us; speedup vs baseline: 1.0920x; 1.0157x over previous
//
#include <hip/hip_runtime.h>
#include <math.h>

#define E_DIM 1024
#define HH 8
#define DH 128
#define BB 32
#define MM 1024
#define NTOK 32768
#define CHUNK 16384
#define CELU_A 1.3f
#define GN_EPS 1e-5f
#define SCALE_F 0.08838834764831845f   // 1/sqrt(128)

typedef unsigned short ushort_t;
typedef __attribute__((ext_vector_type(8))) short short8;
typedef __attribute__((ext_vector_type(4))) float f32x4;

#define MFMA16(a,b,c) __builtin_amdgcn_mfma_f32_16x16x32_bf16((a),(b),(c),0,0,0)

union U8 { short8 v; ushort_t u[8]; };

__device__ __forceinline__ ushort_t f2bf(float f) {
    unsigned u = __float_as_uint(f);
    u += 0x7fffu + ((u >> 16) & 1u);          // round-to-nearest-even
    return (ushort_t)(u >> 16);
}
__device__ __forceinline__ float bf2f(ushort_t h) {
    return __uint_as_float(((unsigned)h) << 16);
}

// async global -> LDS, 16B per lane (wave-linear LDS destination)
__device__ __forceinline__ void gload16(const void* g, void* l) {
    __builtin_amdgcn_global_load_lds(
        (const __attribute__((address_space(1))) unsigned*)g,
        (__attribute__((address_space(3))) unsigned*)l, 16, 0, 0);
}

// ---------------------------------------------------------------------------
// fp32 -> (hi, lo) bf16 planes. Memory-bound, 32B read / 32B write per thread.
// ---------------------------------------------------------------------------
__global__ __launch_bounds__(256)
void split_kernel(const float* __restrict__ in, ushort_t* __restrict__ hi,
                  ushort_t* __restrict__ lo, int n8)
{
    int i = blockIdx.x * 256 + threadIdx.x;
    if (i >= n8) return;
    const float4* p = (const float4*)in;
    float4 a = p[2 * i], b = p[2 * i + 1];
    float f[8] = {a.x, a.y, a.z, a.w, b.x, b.y, b.z, b.w};
    U8 h, l;
#pragma unroll
    for (int j = 0; j < 8; ++j) {
        ushort_t hh = f2bf(f[j]);
        h.u[j] = hh;
        l.u[j] = f2bf(f[j] - bf2f(hh));
    }
    *(short8*)&hi[(size_t)i * 8] = h.v;
    *(short8*)&lo[(size_t)i * 8] = l.v;
}

// ---------------------------------------------------------------------------
// mask [B,M] int -> packed bits, one u32 per (b, 32-col tile).
// ---------------------------------------------------------------------------
__global__ __launch_bounds__(32)
void pack_mask(const int* __restrict__ mask, unsigned* __restrict__ mbits)
{
    int b = blockIdx.x, t = threadIdx.x;
    const int* mp = mask + (size_t)b * MM + t * 32;
    unsigned v = 0;
    for (int j = 0; j < 32; ++j) v |= (mp[j] != 0 ? 1u : 0u) << j;
    mbits[b * 32 + t] = v;
}

// ---------------------------------------------------------------------------
// Pure split-bf16 MFMA GEMM (inputs pre-split), C tile 128x128, 4 waves 2x2.
// C = X @ W^T via 3-term split: Xhi*Whi + Xhi*Wlo + Xlo*Whi.
// Staging: global_load_lds dwordx4 into linear [128][32] bf16 LDS tiles.
// Epilogue in two 64-row halves keeps the union ~34 KB -> 3 blocks/CU.
// MODE 0: bias+CELU+GroupNorm, write split rows [hi128|lo128] -> [B,H,M,256].
// MODE 1: same epilogue, write split TRANSPOSED into vhi/vlo [B,H,D,M].
// MODE 2: A = attn output already split in qsp layout; bias only, fp32 out.
// ---------------------------------------------------------------------------
struct alignas(16) TilesT {
    ushort_t ahi[128 * 32]; ushort_t alo[128 * 32];
    ushort_t bhi[128 * 32]; ushort_t blo[128 * 32];
};
struct alignas(16) EpiT {
    float ybuf[64 * 132]; float mu[64]; float rs[64];
};
union SmemU { TilesT t; EpiT e; };

template<int MODE>
__global__ __launch_bounds__(256, 3)
void proj_kernel(const ushort_t* __restrict__ Ahi, const ushort_t* __restrict__ Alo,
                 const ushort_t* __restrict__ Bhi, const ushort_t* __restrict__ Blo,
                 const float* __restrict__ bias, const float* __restrict__ gamma,
                 const float* __restrict__ beta, int row_off,
                 ushort_t* __restrict__ out0, ushort_t* __restrict__ out1,
                 float* __restrict__ outf)
{
    __shared__ SmemU sm;

    const int tid  = threadIdx.x;
    const int w    = tid >> 6, lane = tid & 63;
    const int quad = lane >> 4, l16 = lane & 15;
    const int wr   = (w >> 1) * 64, wc = (w & 1) * 64;
    const int lrow0 = blockIdx.x * 128;        // row in (chunk-local) A planes
    const int row0  = row_off + lrow0;         // global token row (outputs)
    const int col0  = blockIdx.y * 128;

    f32x4 Cf[4][4];
#pragma unroll
    for (int i = 0; i < 4; ++i)
#pragma unroll
        for (int j = 0; j < 4; ++j) Cf[i][j] = (f32x4){0.f, 0.f, 0.f, 0.f};

    const int s0 = tid, s1 = tid + 256;
    const int ra0 = tid >> 2, ra1 = ra0 + 64;
    const int ga  = (tid & 3) * 8;

    unsigned aoff0 = 0, aoff1 = 0;
    size_t a2b0 = 0, a2b1 = 0;
    if constexpr (MODE == 2) {
        int n0 = row0 + ra0, n1 = row0 + ra1;
        a2b0 = ((size_t)(n0 >> 10) * (HH * MM) + (n0 & 1023)) * 256;
        a2b1 = ((size_t)(n1 >> 10) * (HH * MM) + (n1 & 1023)) * 256;
    } else {
        aoff0 = (unsigned)((lrow0 + ra0) * E_DIM + ga);
        aoff1 = (unsigned)((lrow0 + ra1) * E_DIM + ga);
    }
    const unsigned boff0 = (unsigned)((col0 + ra0) * E_DIM + ga);
    const unsigned boff1 = (unsigned)((col0 + ra1) * E_DIM + ga);

    for (int k0 = 0; k0 < E_DIM; k0 += 32) {
        // ---- stage A ----
        if constexpr (MODE == 2) {
            int e0 = k0 + ga;
            size_t ao = (size_t)(e0 >> 7) * (MM * 256) + (e0 & 127);
            gload16(Ahi + a2b0 + ao,       &sm.t.ahi[s0 * 8]);
            gload16(Ahi + a2b0 + ao + 128, &sm.t.alo[s0 * 8]);
            gload16(Ahi + a2b1 + ao,       &sm.t.ahi[s1 * 8]);
            gload16(Ahi + a2b1 + ao + 128, &sm.t.alo[s1 * 8]);
        } else {
            gload16(Ahi + aoff0 + k0, &sm.t.ahi[s0 * 8]);
            gload16(Alo + aoff0 + k0, &sm.t.alo[s0 * 8]);
            gload16(Ahi + aoff1 + k0, &sm.t.ahi[s1 * 8]);
            gload16(Alo + aoff1 + k0, &sm.t.alo[s1 * 8]);
        }
        // ---- stage B ----
        gload16(Bhi + boff0 + k0, &sm.t.bhi[s0 * 8]);
        gload16(Blo + boff0 + k0, &sm.t.blo[s0 * 8]);
        gload16(Bhi + boff1 + k0, &sm.t.bhi[s1 * 8]);
        gload16(Blo + boff1 + k0, &sm.t.blo[s1 * 8]);
        __syncthreads();   // drains vmcnt(0): tiles resident
        // ---- compute: 16 frag loads, 48 MFMAs ----
        short8 a_hi[4], a_lo[4], b_hi[4], b_lo[4];
#pragma unroll
        for (int mt = 0; mt < 4; ++mt) {
            int r = wr + mt * 16 + l16;
            a_hi[mt] = *(const short8*)&sm.t.ahi[r * 32 + quad * 8];
            a_lo[mt] = *(const short8*)&sm.t.alo[r * 32 + quad * 8];
        }
#pragma unroll
        for (int nt = 0; nt < 4; ++nt) {
            int r = wc + nt * 16 + l16;
            b_hi[nt] = *(const short8*)&sm.t.bhi[r * 32 + quad * 8];
            b_lo[nt] = *(const short8*)&sm.t.blo[r * 32 + quad * 8];
        }
#pragma unroll
        for (int mt = 0; mt < 4; ++mt)
#pragma unroll
            for (int nt = 0; nt < 4; ++nt) {
                f32x4 c = Cf[mt][nt];
                c = MFMA16(a_hi[mt], b_hi[nt], c);
                c = MFMA16(a_hi[mt], b_lo[nt], c);
                c = MFMA16(a_lo[mt], b_hi[nt], c);
                Cf[mt][nt] = c;
            }
        __syncthreads();
    }

    // ---- epilogue ----
    if constexpr (MODE == 2) {
#pragma unroll
        for (int mt = 0; mt < 4; ++mt)
#pragma unroll
            for (int nt = 0; nt < 4; ++nt) {
                int c = col0 + wc + nt * 16 + l16;
                float bv = bias[c];
#pragma unroll
                for (int reg = 0; reg < 4; ++reg) {
                    int r = row0 + wr + mt * 16 + quad * 4 + reg;
                    outf[(size_t)r * E_DIM + c] = Cf[mt][nt][reg] + bv;
                }
            }
    } else {
        for (int h2 = 0; h2 < 2; ++h2) {
            __syncthreads();
            if ((w >> 1) == h2) {
#pragma unroll
                for (int mt = 0; mt < 4; ++mt)
#pragma unroll
                    for (int nt = 0; nt < 4; ++nt) {
                        int c = wc + nt * 16 + l16;
                        float bv = bias[col0 + c];
#pragma unroll
                        for (int reg = 0; reg < 4; ++reg) {
                            int r = mt * 16 + quad * 4 + reg;
                            float x = Cf[mt][nt][reg] + bv;
                            x = x > 0.f ? x : CELU_A * (__expf(x * (1.0f / CELU_A)) - 1.0f);
                            sm.e.ybuf[r * 132 + c] = x;
                        }
                    }
            }
            __syncthreads();
            {   // GroupNorm stats: 4 threads/row, 32 cols each, shfl combine
                int r = tid >> 2, sg = (tid & 3) * 32;
                float s = 0.f, ss = 0.f;
                for (int i = 0; i < 32; i += 4) {
                    float4 v = *(float4*)&sm.e.ybuf[r * 132 + sg + i];
                    s  += v.x + v.y + v.z + v.w;
                    ss += v.x * v.x + v.y * v.y + v.z * v.z + v.w * v.w;
                }
                s  += __shfl_xor(s, 1);  ss += __shfl_xor(ss, 1);
                s  += __shfl_xor(s, 2);  ss += __shfl_xor(ss, 2);
                if ((tid & 3) == 0) {
                    float mu  = s * (1.f / 128.f);
                    float var = ss * (1.f / 128.f) - mu * mu;
                    sm.e.mu[r] = mu;
                    sm.e.rs[r] = rsqrtf(var + GN_EPS);
                }
            }
            __syncthreads();
            if constexpr (MODE == 0) {
                int r = tid >> 2, sg = (tid & 3) * 32;
                int n = row0 + h2 * 64 + r, b = n >> 10, m = n & 1023, h = blockIdx.y;
                float mu = sm.e.mu[r], rs = sm.e.rs[r];
                ushort_t* orow = out0 + ((size_t)((b * HH + h) * MM + m)) * 256;
                for (int i0 = 0; i0 < 32; i0 += 8) {
                    U8 ph, pl;
#pragma unroll
                    for (int j = 0; j < 8; ++j) {
                        int c = sg + i0 + j;
                        float y = (sm.e.ybuf[r * 132 + c] - mu) * rs * gamma[col0 + c] + beta[col0 + c];
                        ushort_t hh = f2bf(y);
                        ph.u[j] = hh; pl.u[j] = f2bf(y - bf2f(hh));
                    }
                    *(short8*)&orow[sg + i0]       = ph.v;
                    *(short8*)&orow[128 + sg + i0] = pl.v;
                }
            } else {  // MODE 1: transposed V write
                int d = tid >> 1, off = (tid & 1) * 32;
                int b = row0 >> 10, m0 = (row0 & 1023) + h2 * 64, h = blockIdx.y;
                float g = gamma[col0 + d], be = beta[col0 + d];
                size_t vbase = ((size_t)(b * HH + h) * DH + d) * MM + m0 + off;
                for (int i0 = 0; i0 < 32; i0 += 8) {
                    U8 ph, pl;
#pragma unroll
                    for (int j = 0; j < 8; ++j) {
                        int rl = off + i0 + j;
                        float y = (sm.e.ybuf[rl * 132 + d] - sm.e.mu[rl]) * sm.e.rs[rl] * g + be;
                        ushort_t hh = f2bf(y);
                        ph.u[j] = hh; pl.u[j] = f2bf(y - bf2f(hh));
                    }
                    *(short8*)&out0[vbase + i0] = ph.v;
                    *(short8*)&out1[vbase + i0] = pl.v;
                }
            }
        }
    }
}

// ---------------------------------------------------------------------------
// Flash attention, MFMA. Block = (b,h) x 64 Q rows, 4 waves (16 rows each).
// Changes vs prev round:
//  - in-register online softmax: C-layout row r=(quad*4+reg) spans 16 lanes,
//    row max/sum via shfl_xor(1,2,4,8); m/l/alpha are lane-local registers.
//    Ss / mask_s / alpha/mrow/lrow LDS removed: 61440 -> 48128 B = 3 blk/CU.
//  - mask via packed bit-words (one uniform u32 load per tile, prefetched).
//  - K/V register prefetch one tile ahead, issued after the stage barrier so
//    latency drains under QK^T+softmax+PV (T14).
//  - XCD-grouping swizzle: all 16 q-blocks of one bh on the same XCD.
//  - 3 barriers/iter (was 4).
// ---------------------------------------------------------------------------
__global__ __launch_bounds__(256, 3)
void attn_kernel(const ushort_t* __restrict__ qsp, const ushort_t* __restrict__ ksp,
                 const ushort_t* __restrict__ vhi_g, const ushort_t* __restrict__ vlo_g,
                 const unsigned* __restrict__ mbits, ushort_t* __restrict__ obuf)
{
    __shared__ __align__(16) ushort_t Ks_hi[32 * 136], Ks_lo[32 * 136];
    __shared__ __align__(16) ushort_t Vt_hi[128 * 40], Vt_lo[128 * 40];
    __shared__ __align__(16) ushort_t Phi_s[64 * 40], Plo_s[64 * 40];

    const int tid  = threadIdx.x;
    const int w    = tid >> 6, lane = tid & 63;
    const int quad = lane >> 4, l16 = lane & 15;
    // XCD-grouping swizzle (bijective): dispatch-linear -> (bh, q-block) such
    // that the 16 q-blocks sharing one bh land on one XCD's L2.
    const int lin = blockIdx.y * 16 + blockIdx.x;
    const int idx = lin >> 3;
    const int bh  = ((idx >> 4) << 3) | (lin & 7);
    const int q0  = (idx & 15) * 64;
    const int b   = bh >> 3;

    short8 qa_hi[4], qa_lo[4];
    {
        const ushort_t* qrow = qsp + ((size_t)bh * MM + q0 + w * 16 + l16) * 256;
#pragma unroll
        for (int kc = 0; kc < 4; ++kc) {
            qa_hi[kc] = *(const short8*)(qrow + kc * 32 + quad * 8);
            qa_lo[kc] = *(const short8*)(qrow + 128 + kc * 32 + quad * 8);
        }
    }
    f32x4 Of[8];
#pragma unroll
    for (int i = 0; i < 8; ++i) Of[i] = (f32x4){0.f, 0.f, 0.f, 0.f};
    float mreg[4] = {-3.0e38f, -3.0e38f, -3.0e38f, -3.0e38f};
    float lreg[4] = {0.f, 0.f, 0.f, 0.f};

    // staging coords + tile-0 preload into registers
    const int kj = tid >> 3, kseg = tid & 7;
    const ushort_t* kbase  = ksp   + ((size_t)bh * MM + kj) * 256 + kseg * 16;
    const int vd = tid >> 1, vhf = tid & 1;
    const ushort_t* vhbase = vhi_g + ((size_t)bh * DH + vd) * MM + vhf * 16;
    const ushort_t* vlbase = vlo_g + ((size_t)bh * DH + vd) * MM + vhf * 16;

    short8 ck0 = *(const short8*)(kbase);
    short8 ck1 = *(const short8*)(kbase + 8);
    short8 ck2 = *(const short8*)(kbase + 128);
    short8 ck3 = *(const short8*)(kbase + 136);
    short8 cv0 = *(const short8*)(vhbase);
    short8 cv1 = *(const short8*)(vhbase + 8);
    short8 cv2 = *(const short8*)(vlbase);
    short8 cv3 = *(const short8*)(vlbase + 8);
    unsigned mw = mbits[b << 5];

    for (int kt = 0; kt < 32; ++kt) {
        // ---- stage tile kt from registers ----
        *(short8*)&Ks_hi[kj * 136 + kseg * 16 + 0] = ck0;
        *(short8*)&Ks_hi[kj * 136 + kseg * 16 + 8] = ck1;
        *(short8*)&Ks_lo[kj * 136 + kseg * 16 + 0] = ck2;
        *(short8*)&Ks_lo[kj * 136 + kseg * 16 + 8] = ck3;
        *(short8*)&Vt_hi[vd * 40 + vhf * 16 + 0] = cv0;
        *(short8*)&Vt_hi[vd * 40 + vhf * 16 + 8] = cv1;
        *(short8*)&Vt_lo[vd * 40 + vhf * 16 + 0] = cv2;
        *(short8*)&Vt_lo[vd * 40 + vhf * 16 + 8] = cv3;
        __syncthreads();
        // ---- prefetch tile kt+1 (wrapped) -> latency hides under compute ----
        {
            int ktn = (kt + 1) & 31;
            const ushort_t* kp  = kbase  + (size_t)ktn * 8192;
            ck0 = *(const short8*)(kp);
            ck1 = *(const short8*)(kp + 8);
            ck2 = *(const short8*)(kp + 128);
            ck3 = *(const short8*)(kp + 136);
            const ushort_t* vhp = vhbase + ktn * 32;
            const ushort_t* vlp = vlbase + ktn * 32;
            cv0 = *(const short8*)(vhp);
            cv1 = *(const short8*)(vhp + 8);
            cv2 = *(const short8*)(vlp);
            cv3 = *(const short8*)(vlp + 8);
        }
        unsigned mw_cur = mw;
        mw = mbits[(b << 5) | ((kt + 1) & 31)];
        // ---- S = split QK^T ----
        f32x4 Sf[2];
        Sf[0] = (f32x4){0.f, 0.f, 0.f, 0.f};
        Sf[1] = (f32x4){0.f, 0.f, 0.f, 0.f};
#pragma unroll
        for (int kc = 0; kc < 4; ++kc) {
#pragma unroll
            for (int ct = 0; ct < 2; ++ct) {
                const short8 kbh = *(const short8*)&Ks_hi[(ct * 16 + l16) * 136 + kc * 32 + quad * 8];
                const short8 kbl = *(const short8*)&Ks_lo[(ct * 16 + l16) * 136 + kc * 32 + quad * 8];
                f32x4 c = Sf[ct];
                c = MFMA16(qa_hi[kc], kbh, c);
                c = MFMA16(qa_hi[kc], kbl, c);
                c = MFMA16(qa_lo[kc], kbh, c);
                Sf[ct] = c;
            }
        }
        // ---- in-register online softmax + split-P write ----
        float al4[4];
#pragma unroll
        for (int reg = 0; reg < 4; ++reg) {
            float s0 = Sf[0][reg] * SCALE_F;
            float s1 = Sf[1][reg] * SCALE_F;
            if (!((mw_cur >> l16) & 1u))        s0 = -1e9f;
            if (!((mw_cur >> (16 + l16)) & 1u)) s1 = -1e9f;
            float pm = fmaxf(s0, s1);
            pm = fmaxf(pm, __shfl_xor(pm, 1));
            pm = fmaxf(pm, __shfl_xor(pm, 2));
            pm = fmaxf(pm, __shfl_xor(pm, 4));
            pm = fmaxf(pm, __shfl_xor(pm, 8));
            float mo = mreg[reg];
            float mx = fmaxf(mo, pm);
            float al = __expf(mo - mx);
            float p0 = __expf(s0 - mx);
            float p1 = __expf(s1 - mx);
            float ps = p0 + p1;
            ps += __shfl_xor(ps, 1);
            ps += __shfl_xor(ps, 2);
            ps += __shfl_xor(ps, 4);
            ps += __shfl_xor(ps, 8);
            mreg[reg] = mx;
            lreg[reg] = lreg[reg] * al + ps;
            al4[reg] = al;
            int rr = (w << 4) + (quad << 2) + reg;
            ushort_t h0 = f2bf(p0), h1 = f2bf(p1);
            Phi_s[rr * 40 + l16]      = h0;
            Phi_s[rr * 40 + 16 + l16] = h1;
            Plo_s[rr * 40 + l16]      = f2bf(p0 - bf2f(h0));
            Plo_s[rr * 40 + 16 + l16] = f2bf(p1 - bf2f(h1));
        }
        __syncthreads();
        // ---- O = O*alpha + split P@V ----
        {
            const short8 pah = *(const short8*)&Phi_s[(w * 16 + l16) * 40 + quad * 8];
            const short8 pal = *(const short8*)&Plo_s[(w * 16 + l16) * 40 + quad * 8];
#pragma unroll
            for (int ct = 0; ct < 8; ++ct) {
                f32x4 c = Of[ct];
#pragma unroll
                for (int reg = 0; reg < 4; ++reg) c[reg] *= al4[reg];
                const short8 vbh = *(const short8*)&Vt_hi[(ct * 16 + l16) * 40 + quad * 8];
                const short8 vbl = *(const short8*)&Vt_lo[(ct * 16 + l16) * 40 + quad * 8];
                c = MFMA16(pah, vbh, c);
                c = MFMA16(pah, vbl, c);
                c = MFMA16(pal, vbh, c);
                Of[ct] = c;
            }
        }
        __syncthreads();   // Ks/Vt/Phi free for next iteration's stage
    }
    // ---- epilogue: O/l -> split bf16, overwrite q rows in qsp layout ----
    {
        float li[4];
#pragma unroll
        for (int reg = 0; reg < 4; ++reg) li[reg] = 1.f / lreg[reg];
#pragma unroll
        for (int ct = 0; ct < 8; ++ct)
#pragma unroll
            for (int reg = 0; reg < 4; ++reg) {
                float v = Of[ct][reg] * li[reg];
                ushort_t hh = f2bf(v);
                ushort_t ll = f2bf(v - bf2f(hh));
                size_t rb = ((size_t)bh * MM + q0 + w * 16 + quad * 4 + reg) * 256 + ct * 16 + l16;
                obuf[rb]       = hh;
                obuf[rb + 128] = ll;
            }
    }
}

// ---------------------------------------------------------------------------
// Launch schedule / workspace choreography (ws = 384MB, unchanged layout):
//   qsp [134MB] | ksp [134MB] | vhi [67MB] | vlo [67MB]
// d_out (134MB) doubles as scratch until the final projection:
//   xhi/xlo chunk X splits @ 0..64MB, Wk split @ 64MB, mask bits @ ~84MB.
//   Wv -> qsp region, Wq -> ksp region, Wm -> ksp region (after attn).
// ---------------------------------------------------------------------------
extern "C" void kernel_launch(void* const* d_in, const int* in_sizes, int n_in,
                              void* d_out, int out_size, void* d_ws, size_t ws_size,
                              hipStream_t stream)
{
    const float* query  = (const float*)d_in[0];
    const float* key    = (const float*)d_in[1];
    const int*   mask   = (const int*)d_in[2];
    // d_in[3] = value1 (unused by reference)
    const float* value2 = (const float*)d_in[4];
    const float* Wq = (const float*)d_in[5];
    const float* bq = (const float*)d_in[6];
    const float* gq = (const float*)d_in[7];
    const float* betaq = (const float*)d_in[8];
    const float* Wk = (const float*)d_in[9];
    const float* bk = (const float*)d_in[10];
    const float* gk = (const float*)d_in[11];
    const float* betak = (const float*)d_in[12];
    const float* Wv = (const float*)d_in[13];
    const float* bv = (const float*)d_in[14];
    const float* gv = (const float*)d_in[15];
    const float* betav = (const float*)d_in[16];
    const float* Wm = (const float*)d_in[17];
    const float* bm = (const float*)d_in[18];
    float* out = (float*)d_out;

    ushort_t* qsp = (ushort_t*)d_ws;                       // [B,H,M, hi128|lo128]
    ushort_t* ksp = qsp + (size_t)67108864;
    ushort_t* vhi = ksp + (size_t)67108864;                // [B,H,D,M]
    ushort_t* vlo = vhi + (size_t)33554432;

    ushort_t* ob    = (ushort_t*)d_out;
    ushort_t* xhi   = ob;                                  // chunk X scratch
    ushort_t* xlo   = ob + (size_t)CHUNK * E_DIM;
    ushort_t* wkhi  = ob + (size_t)2 * CHUNK * E_DIM;      // Wk split @ +64MB
    ushort_t* wklo  = wkhi + (size_t)E_DIM * E_DIM;
    unsigned* mbits = (unsigned*)(ob + (size_t)41943040);  // mask bits @ ~84MB
    ushort_t* wvhi  = qsp;                                 // Wv split in qsp region
    ushort_t* wvlo  = wvhi + (size_t)E_DIM * E_DIM;
    ushort_t* wqhi  = ksp;                                 // Wq split in ksp region
    ushort_t* wqlo  = wqhi + (size_t)E_DIM * E_DIM;
    ushort_t* wmhi  = ksp;                                 // Wm split (after attn)
    ushort_t* wmlo  = wmhi + (size_t)E_DIM * E_DIM;

    const int WN8 = (E_DIM * E_DIM) / 8;       // 131072
    const int XN8 = (CHUNK * E_DIM) / 8;       // 2097152

    pack_mask<<<BB, 32, 0, stream>>>(mask, mbits);
    split_kernel<<<WN8 / 256, 256, 0, stream>>>(Wv, wvhi, wvlo, WN8);
    split_kernel<<<WN8 / 256, 256, 0, stream>>>(Wq, wqhi, wqlo, WN8);
    split_kernel<<<WN8 / 256, 256, 0, stream>>>(Wk, wkhi, wklo, WN8);

    dim3 gproj(CHUNK / 128, E_DIM / 128);      // (128, 8)

    for (int c = 0; c < 2; ++c) {
        split_kernel<<<XN8 / 256, 256, 0, stream>>>(value2 + (size_t)c * CHUNK * E_DIM, xhi, xlo, XN8);
        proj_kernel<1><<<gproj, 256, 0, stream>>>(xhi, xlo, wvhi, wvlo, bv, gv, betav,
                                                  c * CHUNK, vhi, vlo, nullptr);
    }
    for (int c = 0; c < 2; ++c) {
        split_kernel<<<XN8 / 256, 256, 0, stream>>>(query + (size_t)c * CHUNK * E_DIM, xhi, xlo, XN8);
        proj_kernel<0><<<gproj, 256, 0, stream>>>(xhi, xlo, wqhi, wqlo, bq, gq, betaq,
                                                  c * CHUNK, qsp, nullptr, nullptr);
    }
    for (int c = 0; c < 2; ++c) {
        split_kernel<<<XN8 / 256, 256, 0, stream>>>(key + (size_t)c * CHUNK * E_DIM, xhi, xlo, XN8);
        proj_kernel<0><<<gproj, 256, 0, stream>>>(xhi, xlo, wkhi, wklo, bk, gk, betak,
                                                  c * CHUNK, ksp, nullptr, nullptr);
    }

    attn_kernel<<<dim3(MM / 64, BB * HH), 256, 0, stream>>>(qsp, ksp, vhi, vlo, mbits, qsp);

    split_kernel<<<WN8 / 256, 256, 0, stream>>>(Wm, wmhi, wmlo, WN8);
    proj_kernel<2><<<dim3(NTOK / 128, E_DIM / 128), 256, 0, stream>>>(
        qsp, nullptr, wmhi, wmlo, bm, nullptr, nullptr, 0, nullptr, nullptr, out);
}

// Round 5
// 2033.872 us; speedup vs baseline: 1.1758x; 1.0768x over previous
//
#include <hip/hip_runtime.h>
#include <math.h>

#define E_DIM 1024
#define HH 8
#define DH 128
#define BB 32
#define MM 1024
#define NTOK 32768
#define CHUNK 16384
#define CELU_A 1.3f
#define GN_EPS 1e-5f
#define SCALE_F 0.08838834764831845f   // 1/sqrt(128)

typedef unsigned short ushort_t;
typedef __attribute__((ext_vector_type(8))) short short8;
typedef __attribute__((ext_vector_type(4))) float f32x4;
typedef __attribute__((ext_vector_type(16))) float f32x16;

#define MFMA16(a,b,c) __builtin_amdgcn_mfma_f32_16x16x32_bf16((a),(b),(c),0,0,0)
#define MFMA32(a,b,c) __builtin_amdgcn_mfma_f32_32x32x16_bf16((a),(b),(c),0,0,0)

union U8 { short8 v; ushort_t u[8]; };
union U32x4 { unsigned u[4]; short8 v; };

__device__ __forceinline__ ushort_t f2bf(float f) {
    unsigned u = __float_as_uint(f);
    u += 0x7fffu + ((u >> 16) & 1u);          // round-to-nearest-even
    return (ushort_t)(u >> 16);
}
__device__ __forceinline__ float bf2f(ushort_t h) {
    return __uint_as_float(((unsigned)h) << 16);
}

// async global -> LDS, 16B per lane (wave-linear LDS destination)
__device__ __forceinline__ void gload16(const void* g, void* l) {
    __builtin_amdgcn_global_load_lds(
        (const __attribute__((address_space(1))) unsigned*)g,
        (__attribute__((address_space(3))) unsigned*)l, 16, 0, 0);
}

// ---------------------------------------------------------------------------
// fp32 -> (hi, lo) bf16 planes. Memory-bound, 32B read / 32B write per thread.
// ---------------------------------------------------------------------------
__global__ __launch_bounds__(256)
void split_kernel(const float* __restrict__ in, ushort_t* __restrict__ hi,
                  ushort_t* __restrict__ lo, int n8)
{
    int i = blockIdx.x * 256 + threadIdx.x;
    if (i >= n8) return;
    const float4* p = (const float4*)in;
    float4 a = p[2 * i], b = p[2 * i + 1];
    float f[8] = {a.x, a.y, a.z, a.w, b.x, b.y, b.z, b.w};
    U8 h, l;
#pragma unroll
    for (int j = 0; j < 8; ++j) {
        ushort_t hh = f2bf(f[j]);
        h.u[j] = hh;
        l.u[j] = f2bf(f[j] - bf2f(hh));
    }
    *(short8*)&hi[(size_t)i * 8] = h.v;
    *(short8*)&lo[(size_t)i * 8] = l.v;
}

// ---------------------------------------------------------------------------
// mask [B,M] int -> packed bits, one u32 per (b, 32-col tile).
// ---------------------------------------------------------------------------
__global__ __launch_bounds__(32)
void pack_mask(const int* __restrict__ mask, unsigned* __restrict__ mbits)
{
    int b = blockIdx.x, t = threadIdx.x;
    const int* mp = mask + (size_t)b * MM + t * 32;
    unsigned v = 0;
    for (int j = 0; j < 32; ++j) v |= (mp[j] != 0 ? 1u : 0u) << j;
    mbits[b * 32 + t] = v;
}

// ---------------------------------------------------------------------------
// Pure split-bf16 MFMA GEMM (inputs pre-split), C tile 128x128, 4 waves 2x2.
// C = X @ W^T via 3-term split: Xhi*Whi + Xhi*Wlo + Xlo*Whi.
// Staging: global_load_lds dwordx4 into linear [128][32] bf16 LDS tiles.
// Epilogue in two 64-row halves keeps the union ~34 KB -> 3 blocks/CU.
// ---------------------------------------------------------------------------
struct alignas(16) TilesT {
    ushort_t ahi[128 * 32]; ushort_t alo[128 * 32];
    ushort_t bhi[128 * 32]; ushort_t blo[128 * 32];
};
struct alignas(16) EpiT {
    float ybuf[64 * 132]; float mu[64]; float rs[64];
};
union SmemU { TilesT t; EpiT e; };

template<int MODE>
__global__ __launch_bounds__(256, 3)
void proj_kernel(const ushort_t* __restrict__ Ahi, const ushort_t* __restrict__ Alo,
                 const ushort_t* __restrict__ Bhi, const ushort_t* __restrict__ Blo,
                 const float* __restrict__ bias, const float* __restrict__ gamma,
                 const float* __restrict__ beta, int row_off,
                 ushort_t* __restrict__ out0, ushort_t* __restrict__ out1,
                 float* __restrict__ outf)
{
    __shared__ SmemU sm;

    const int tid  = threadIdx.x;
    const int w    = tid >> 6, lane = tid & 63;
    const int quad = lane >> 4, l16 = lane & 15;
    const int wr   = (w >> 1) * 64, wc = (w & 1) * 64;
    const int lrow0 = blockIdx.x * 128;        // row in (chunk-local) A planes
    const int row0  = row_off + lrow0;         // global token row (outputs)
    const int col0  = blockIdx.y * 128;

    f32x4 Cf[4][4];
#pragma unroll
    for (int i = 0; i < 4; ++i)
#pragma unroll
        for (int j = 0; j < 4; ++j) Cf[i][j] = (f32x4){0.f, 0.f, 0.f, 0.f};

    const int s0 = tid, s1 = tid + 256;
    const int ra0 = tid >> 2, ra1 = ra0 + 64;
    const int ga  = (tid & 3) * 8;

    unsigned aoff0 = 0, aoff1 = 0;
    size_t a2b0 = 0, a2b1 = 0;
    if constexpr (MODE == 2) {
        int n0 = row0 + ra0, n1 = row0 + ra1;
        a2b0 = ((size_t)(n0 >> 10) * (HH * MM) + (n0 & 1023)) * 256;
        a2b1 = ((size_t)(n1 >> 10) * (HH * MM) + (n1 & 1023)) * 256;
    } else {
        aoff0 = (unsigned)((lrow0 + ra0) * E_DIM + ga);
        aoff1 = (unsigned)((lrow0 + ra1) * E_DIM + ga);
    }
    const unsigned boff0 = (unsigned)((col0 + ra0) * E_DIM + ga);
    const unsigned boff1 = (unsigned)((col0 + ra1) * E_DIM + ga);

    for (int k0 = 0; k0 < E_DIM; k0 += 32) {
        // ---- stage A ----
        if constexpr (MODE == 2) {
            int e0 = k0 + ga;
            size_t ao = (size_t)(e0 >> 7) * (MM * 256) + (e0 & 127);
            gload16(Ahi + a2b0 + ao,       &sm.t.ahi[s0 * 8]);
            gload16(Ahi + a2b0 + ao + 128, &sm.t.alo[s0 * 8]);
            gload16(Ahi + a2b1 + ao,       &sm.t.ahi[s1 * 8]);
            gload16(Ahi + a2b1 + ao + 128, &sm.t.alo[s1 * 8]);
        } else {
            gload16(Ahi + aoff0 + k0, &sm.t.ahi[s0 * 8]);
            gload16(Alo + aoff0 + k0, &sm.t.alo[s0 * 8]);
            gload16(Ahi + aoff1 + k0, &sm.t.ahi[s1 * 8]);
            gload16(Alo + aoff1 + k0, &sm.t.alo[s1 * 8]);
        }
        // ---- stage B ----
        gload16(Bhi + boff0 + k0, &sm.t.bhi[s0 * 8]);
        gload16(Blo + boff0 + k0, &sm.t.blo[s0 * 8]);
        gload16(Bhi + boff1 + k0, &sm.t.bhi[s1 * 8]);
        gload16(Blo + boff1 + k0, &sm.t.blo[s1 * 8]);
        __syncthreads();   // drains vmcnt(0): tiles resident
        // ---- compute: 16 frag loads, 48 MFMAs ----
        short8 a_hi[4], a_lo[4], b_hi[4], b_lo[4];
#pragma unroll
        for (int mt = 0; mt < 4; ++mt) {
            int r = wr + mt * 16 + l16;
            a_hi[mt] = *(const short8*)&sm.t.ahi[r * 32 + quad * 8];
            a_lo[mt] = *(const short8*)&sm.t.alo[r * 32 + quad * 8];
        }
#pragma unroll
        for (int nt = 0; nt < 4; ++nt) {
            int r = wc + nt * 16 + l16;
            b_hi[nt] = *(const short8*)&sm.t.bhi[r * 32 + quad * 8];
            b_lo[nt] = *(const short8*)&sm.t.blo[r * 32 + quad * 8];
        }
#pragma unroll
        for (int mt = 0; mt < 4; ++mt)
#pragma unroll
            for (int nt = 0; nt < 4; ++nt) {
                f32x4 c = Cf[mt][nt];
                c = MFMA16(a_hi[mt], b_hi[nt], c);
                c = MFMA16(a_hi[mt], b_lo[nt], c);
                c = MFMA16(a_lo[mt], b_hi[nt], c);
                Cf[mt][nt] = c;
            }
        __syncthreads();
    }

    // ---- epilogue ----
    if constexpr (MODE == 2) {
#pragma unroll
        for (int mt = 0; mt < 4; ++mt)
#pragma unroll
            for (int nt = 0; nt < 4; ++nt) {
                int c = col0 + wc + nt * 16 + l16;
                float bv = bias[c];
#pragma unroll
                for (int reg = 0; reg < 4; ++reg) {
                    int r = row0 + wr + mt * 16 + quad * 4 + reg;
                    outf[(size_t)r * E_DIM + c] = Cf[mt][nt][reg] + bv;
                }
            }
    } else {
        for (int h2 = 0; h2 < 2; ++h2) {
            __syncthreads();
            if ((w >> 1) == h2) {
#pragma unroll
                for (int mt = 0; mt < 4; ++mt)
#pragma unroll
                    for (int nt = 0; nt < 4; ++nt) {
                        int c = wc + nt * 16 + l16;
                        float bv = bias[col0 + c];
#pragma unroll
                        for (int reg = 0; reg < 4; ++reg) {
                            int r = mt * 16 + quad * 4 + reg;
                            float x = Cf[mt][nt][reg] + bv;
                            x = x > 0.f ? x : CELU_A * (__expf(x * (1.0f / CELU_A)) - 1.0f);
                            sm.e.ybuf[r * 132 + c] = x;
                        }
                    }
            }
            __syncthreads();
            {   // GroupNorm stats: 4 threads/row, 32 cols each, shfl combine
                int r = tid >> 2, sg = (tid & 3) * 32;
                float s = 0.f, ss = 0.f;
                for (int i = 0; i < 32; i += 4) {
                    float4 v = *(float4*)&sm.e.ybuf[r * 132 + sg + i];
                    s  += v.x + v.y + v.z + v.w;
                    ss += v.x * v.x + v.y * v.y + v.z * v.z + v.w * v.w;
                }
                s  += __shfl_xor(s, 1);  ss += __shfl_xor(ss, 1);
                s  += __shfl_xor(s, 2);  ss += __shfl_xor(ss, 2);
                if ((tid & 3) == 0) {
                    float mu  = s * (1.f / 128.f);
                    float var = ss * (1.f / 128.f) - mu * mu;
                    sm.e.mu[r] = mu;
                    sm.e.rs[r] = rsqrtf(var + GN_EPS);
                }
            }
            __syncthreads();
            if constexpr (MODE == 0) {
                int r = tid >> 2, sg = (tid & 3) * 32;
                int n = row0 + h2 * 64 + r, b = n >> 10, m = n & 1023, h = blockIdx.y;
                float mu = sm.e.mu[r], rs = sm.e.rs[r];
                ushort_t* orow = out0 + ((size_t)((b * HH + h) * MM + m)) * 256;
                for (int i0 = 0; i0 < 32; i0 += 8) {
                    U8 ph, pl;
#pragma unroll
                    for (int j = 0; j < 8; ++j) {
                        int c = sg + i0 + j;
                        float y = (sm.e.ybuf[r * 132 + c] - mu) * rs * gamma[col0 + c] + beta[col0 + c];
                        ushort_t hh = f2bf(y);
                        ph.u[j] = hh; pl.u[j] = f2bf(y - bf2f(hh));
                    }
                    *(short8*)&orow[sg + i0]       = ph.v;
                    *(short8*)&orow[128 + sg + i0] = pl.v;
                }
            } else {  // MODE 1: transposed V write
                int d = tid >> 1, off = (tid & 1) * 32;
                int b = row0 >> 10, m0 = (row0 & 1023) + h2 * 64, h = blockIdx.y;
                float g = gamma[col0 + d], be = beta[col0 + d];
                size_t vbase = ((size_t)(b * HH + h) * DH + d) * MM + m0 + off;
                for (int i0 = 0; i0 < 32; i0 += 8) {
                    U8 ph, pl;
#pragma unroll
                    for (int j = 0; j < 8; ++j) {
                        int rl = off + i0 + j;
                        float y = (sm.e.ybuf[rl * 132 + d] - sm.e.mu[rl]) * sm.e.rs[rl] * g + be;
                        ushort_t hh = f2bf(y);
                        ph.u[j] = hh; pl.u[j] = f2bf(y - bf2f(hh));
                    }
                    *(short8*)&out0[vbase + i0] = ph.v;
                    *(short8*)&out1[vbase + i0] = pl.v;
                }
            }
        }
    }
}

// ---------------------------------------------------------------------------
// Flash attention, swapped-operand 32x32x16 MFMA. Block = (b,h) x 128 Q rows,
// 4 waves x 32 q each. Per wave-iter: S^T = K·Q^T (lane owns q-col = lane&31,
// k-rows in C layout), softmax fully lane-local (15 fmax + shfl_xor(32)),
// P stays IN REGISTER: PV B-frags assembled via 8 half-wave shfl exchanges.
// O^T = V^T·P^T so alpha/l rescale is lane-local. No P LDS, 2 barriers/iter,
// LDS reads/token halved vs 16-row waves (the round-4 LDS-throughput bound).
// ---------------------------------------------------------------------------
__global__ __launch_bounds__(256, 2)
void attn_kernel(const ushort_t* __restrict__ qsp, const ushort_t* __restrict__ ksp,
                 const ushort_t* __restrict__ vhi_g, const ushort_t* __restrict__ vlo_g,
                 const unsigned* __restrict__ mbits, ushort_t* __restrict__ obuf)
{
    __shared__ __align__(16) ushort_t Ks_hi[32 * 136], Ks_lo[32 * 136];
    __shared__ __align__(16) ushort_t Vt_hi[128 * 40], Vt_lo[128 * 40];

    const int tid  = threadIdx.x;
    const int w    = tid >> 6, lane = tid & 63;
    const int l32  = lane & 31, h = lane >> 5;
    // XCD grouping: gridDim.x = 8; lin%8 = blockIdx.x -> bh%8 pins the XCD,
    // so all 8 q-blocks of one bh share one L2 (round-4: FETCH 5.5x drop).
    const int bh = ((blockIdx.y >> 3) << 3) | blockIdx.x;
    const int q0 = (blockIdx.y & 7) * 128;
    const int b  = bh >> 3;

    // Q as B-fragments: col q = l32, k-dim d = kc*16 + h*8 + j
    short8 qb_hi[8], qb_lo[8];
    {
        const ushort_t* qrow = qsp + ((size_t)bh * MM + q0 + w * 32 + l32) * 256 + h * 8;
#pragma unroll
        for (int kc = 0; kc < 8; ++kc) {
            qb_hi[kc] = *(const short8*)(qrow + kc * 16);
            qb_lo[kc] = *(const short8*)(qrow + 128 + kc * 16);
        }
    }
    f32x16 Of[4];
#pragma unroll
    for (int i = 0; i < 4; ++i)
#pragma unroll
        for (int r = 0; r < 16; ++r) Of[i][r] = 0.f;
    float m_old = -3.0e38f, l_run = 0.f;

    // staging coords + tile-0 preload into registers
    const int kj = tid >> 3, kseg = tid & 7;
    const ushort_t* kbase  = ksp   + ((size_t)bh * MM + kj) * 256 + kseg * 16;
    const int vd = tid >> 1, vhf = tid & 1;
    const ushort_t* vhbase = vhi_g + ((size_t)bh * DH + vd) * MM + vhf * 16;
    const ushort_t* vlbase = vlo_g + ((size_t)bh * DH + vd) * MM + vhf * 16;

    short8 ck0 = *(const short8*)(kbase);
    short8 ck1 = *(const short8*)(kbase + 8);
    short8 ck2 = *(const short8*)(kbase + 128);
    short8 ck3 = *(const short8*)(kbase + 136);
    short8 cv0 = *(const short8*)(vhbase);
    short8 cv1 = *(const short8*)(vhbase + 8);
    short8 cv2 = *(const short8*)(vlbase);
    short8 cv3 = *(const short8*)(vlbase + 8);
    unsigned mw = mbits[b << 5];

    for (int kt = 0; kt < 32; ++kt) {
        // ---- stage tile kt from registers ----
        *(short8*)&Ks_hi[kj * 136 + kseg * 16 + 0] = ck0;
        *(short8*)&Ks_hi[kj * 136 + kseg * 16 + 8] = ck1;
        *(short8*)&Ks_lo[kj * 136 + kseg * 16 + 0] = ck2;
        *(short8*)&Ks_lo[kj * 136 + kseg * 16 + 8] = ck3;
        *(short8*)&Vt_hi[vd * 40 + vhf * 16 + 0] = cv0;
        *(short8*)&Vt_hi[vd * 40 + vhf * 16 + 8] = cv1;
        *(short8*)&Vt_lo[vd * 40 + vhf * 16 + 0] = cv2;
        *(short8*)&Vt_lo[vd * 40 + vhf * 16 + 8] = cv3;
        __syncthreads();
        // ---- prefetch tile kt+1 (wrapped): latency hides under compute ----
        {
            int ktn = (kt + 1) & 31;
            const ushort_t* kp  = kbase  + (size_t)ktn * 8192;
            ck0 = *(const short8*)(kp);
            ck1 = *(const short8*)(kp + 8);
            ck2 = *(const short8*)(kp + 128);
            ck3 = *(const short8*)(kp + 136);
            const ushort_t* vhp = vhbase + ktn * 32;
            const ushort_t* vlp = vlbase + ktn * 32;
            cv0 = *(const short8*)(vhp);
            cv1 = *(const short8*)(vhp + 8);
            cv2 = *(const short8*)(vlp);
            cv3 = *(const short8*)(vlp + 8);
        }
        unsigned mw_cur = mw;
        mw = mbits[(b << 5) | ((kt + 1) & 31)];

        // ---- S^T = K · Q^T (3-term split, 32x32x16) ----
        f32x16 Sf;
#pragma unroll
        for (int r = 0; r < 16; ++r) Sf[r] = 0.f;
#pragma unroll
        for (int kc = 0; kc < 8; ++kc) {
            const short8 ka = *(const short8*)&Ks_hi[l32 * 136 + h * 8 + kc * 16];
            const short8 kl = *(const short8*)&Ks_lo[l32 * 136 + h * 8 + kc * 16];
            Sf = MFMA32(ka, qb_hi[kc], Sf);
            Sf = MFMA32(ka, qb_lo[kc], Sf);
            Sf = MFMA32(kl, qb_hi[kc], Sf);
        }
        // ---- lane-local online softmax (q = l32; k-row = (r&3)+8*(r>>2)+4h) ----
        float sv[16];
        float pm = -3.0e38f;
#pragma unroll
        for (int r = 0; r < 16; ++r) {
            int kk = (r & 3) + 8 * (r >> 2) + 4 * h;
            float s = Sf[r] * SCALE_F;
            if (!((mw_cur >> kk) & 1u)) s = -1e9f;
            sv[r] = s;
            pm = fmaxf(pm, s);
        }
        pm = fmaxf(pm, __shfl_xor(pm, 32));
        float mx = fmaxf(m_old, pm);
        float al = __expf(m_old - mx);
        float ps = 0.f;
#pragma unroll
        for (int r = 0; r < 16; ++r) { float p = __expf(sv[r] - mx); sv[r] = p; ps += p; }
        ps += __shfl_xor(ps, 32);
        m_old = mx;
        l_run = l_run * al + ps;

        // ---- pack split-P per group g (rows g*8 + 4h + j) ----
        unsigned pa_h[4], pb_h[4], pa_l[4], pb_l[4];
#pragma unroll
        for (int g = 0; g < 4; ++g) {
            ushort_t h0 = f2bf(sv[g*4+0]), h1 = f2bf(sv[g*4+1]);
            ushort_t h2 = f2bf(sv[g*4+2]), h3 = f2bf(sv[g*4+3]);
            pa_h[g] = (unsigned)h0 | ((unsigned)h1 << 16);
            pb_h[g] = (unsigned)h2 | ((unsigned)h3 << 16);
            ushort_t l0 = f2bf(sv[g*4+0] - bf2f(h0)), l1 = f2bf(sv[g*4+1] - bf2f(h1));
            ushort_t l2 = f2bf(sv[g*4+2] - bf2f(h2)), l3 = f2bf(sv[g*4+3] - bf2f(h3));
            pa_l[g] = (unsigned)l0 | ((unsigned)l1 << 16);
            pb_l[g] = (unsigned)l2 | ((unsigned)l3 << 16);
        }
        // ---- assemble PV B-frags via half-wave exchange (lane needs group 2kc+h) ----
        short8 pf_h[2], pf_l[2];
#pragma unroll
        for (int kc = 0; kc < 2; ++kc) {
            U32x4 fh, fl;
            {
                unsigned ta = h ? pa_h[2*kc] : pa_h[2*kc+1];
                unsigned tb = h ? pb_h[2*kc] : pb_h[2*kc+1];
                unsigned ra = (unsigned)__shfl_xor((int)ta, 32);
                unsigned rb = (unsigned)__shfl_xor((int)tb, 32);
                fh.u[0] = h ? ra : pa_h[2*kc];
                fh.u[1] = h ? rb : pb_h[2*kc];
                fh.u[2] = h ? pa_h[2*kc+1] : ra;
                fh.u[3] = h ? pb_h[2*kc+1] : rb;
            }
            {
                unsigned ta = h ? pa_l[2*kc] : pa_l[2*kc+1];
                unsigned tb = h ? pb_l[2*kc] : pb_l[2*kc+1];
                unsigned ra = (unsigned)__shfl_xor((int)ta, 32);
                unsigned rb = (unsigned)__shfl_xor((int)tb, 32);
                fl.u[0] = h ? ra : pa_l[2*kc];
                fl.u[1] = h ? rb : pb_l[2*kc];
                fl.u[2] = h ? pa_l[2*kc+1] : ra;
                fl.u[3] = h ? pb_l[2*kc+1] : rb;
            }
            pf_h[kc] = fh.v; pf_l[kc] = fl.v;
        }
        // ---- O^T = O^T*al + V^T · P^T (3-term) ----
#pragma unroll
        for (int dg = 0; dg < 4; ++dg) {
            f32x16 c = Of[dg];
#pragma unroll
            for (int r = 0; r < 16; ++r) c[r] *= al;
#pragma unroll
            for (int kc = 0; kc < 2; ++kc) {
                const short8 va = *(const short8*)&Vt_hi[(dg * 32 + l32) * 40 + h * 8 + kc * 16];
                const short8 vl = *(const short8*)&Vt_lo[(dg * 32 + l32) * 40 + h * 8 + kc * 16];
                c = MFMA32(va, pf_h[kc], c);
                c = MFMA32(va, pf_l[kc], c);
                c = MFMA32(vl, pf_h[kc], c);
            }
            Of[dg] = c;
        }
        __syncthreads();   // Ks/Vt free for next iteration's stage
    }
    // ---- epilogue: O/l -> split bf16, overwrite q rows in qsp layout ----
    {
        float inv = 1.f / l_run;
        ushort_t* orow = obuf + ((size_t)bh * MM + q0 + w * 32 + l32) * 256;
#pragma unroll
        for (int dg = 0; dg < 4; ++dg)
#pragma unroll
            for (int r = 0; r < 16; ++r) {
                int d = dg * 32 + (r & 3) + 8 * (r >> 2) + 4 * h;
                float v = Of[dg][r] * inv;
                ushort_t hh = f2bf(v);
                orow[d]       = hh;
                orow[128 + d] = f2bf(v - bf2f(hh));
            }
    }
}

// ---------------------------------------------------------------------------
// Launch schedule / workspace choreography (ws = 384MB, unchanged layout):
//   qsp [134MB] | ksp [134MB] | vhi [67MB] | vlo [67MB]
// d_out (134MB) doubles as scratch until the final projection:
//   xhi/xlo chunk X splits @ 0..64MB, Wk split @ 64MB, mask bits @ ~84MB.
//   Wv -> qsp region, Wq -> ksp region, Wm -> ksp region (after attn).
// ---------------------------------------------------------------------------
extern "C" void kernel_launch(void* const* d_in, const int* in_sizes, int n_in,
                              void* d_out, int out_size, void* d_ws, size_t ws_size,
                              hipStream_t stream)
{
    const float* query  = (const float*)d_in[0];
    const float* key    = (const float*)d_in[1];
    const int*   mask   = (const int*)d_in[2];
    // d_in[3] = value1 (unused by reference)
    const float* value2 = (const float*)d_in[4];
    const float* Wq = (const float*)d_in[5];
    const float* bq = (const float*)d_in[6];
    const float* gq = (const float*)d_in[7];
    const float* betaq = (const float*)d_in[8];
    const float* Wk = (const float*)d_in[9];
    const float* bk = (const float*)d_in[10];
    const float* gk = (const float*)d_in[11];
    const float* betak = (const float*)d_in[12];
    const float* Wv = (const float*)d_in[13];
    const float* bv = (const float*)d_in[14];
    const float* gv = (const float*)d_in[15];
    const float* betav = (const float*)d_in[16];
    const float* Wm = (const float*)d_in[17];
    const float* bm = (const float*)d_in[18];
    float* out = (float*)d_out;

    ushort_t* qsp = (ushort_t*)d_ws;                       // [B,H,M, hi128|lo128]
    ushort_t* ksp = qsp + (size_t)67108864;
    ushort_t* vhi = ksp + (size_t)67108864;                // [B,H,D,M]
    ushort_t* vlo = vhi + (size_t)33554432;

    ushort_t* ob    = (ushort_t*)d_out;
    ushort_t* xhi   = ob;                                  // chunk X scratch
    ushort_t* xlo   = ob + (size_t)CHUNK * E_DIM;
    ushort_t* wkhi  = ob + (size_t)2 * CHUNK * E_DIM;      // Wk split @ +64MB
    ushort_t* wklo  = wkhi + (size_t)E_DIM * E_DIM;
    unsigned* mbits = (unsigned*)(ob + (size_t)41943040);  // mask bits @ ~84MB
    ushort_t* wvhi  = qsp;                                 // Wv split in qsp region
    ushort_t* wvlo  = wvhi + (size_t)E_DIM * E_DIM;
    ushort_t* wqhi  = ksp;                                 // Wq split in ksp region
    ushort_t* wqlo  = wqhi + (size_t)E_DIM * E_DIM;
    ushort_t* wmhi  = ksp;                                 // Wm split (after attn)
    ushort_t* wmlo  = wmhi + (size_t)E_DIM * E_DIM;

    const int WN8 = (E_DIM * E_DIM) / 8;       // 131072
    const int XN8 = (CHUNK * E_DIM) / 8;       // 2097152

    pack_mask<<<BB, 32, 0, stream>>>(mask, mbits);
    split_kernel<<<WN8 / 256, 256, 0, stream>>>(Wv, wvhi, wvlo, WN8);
    split_kernel<<<WN8 / 256, 256, 0, stream>>>(Wq, wqhi, wqlo, WN8);
    split_kernel<<<WN8 / 256, 256, 0, stream>>>(Wk, wkhi, wklo, WN8);

    dim3 gproj(CHUNK / 128, E_DIM / 128);      // (128, 8)

    for (int c = 0; c < 2; ++c) {
        split_kernel<<<XN8 / 256, 256, 0, stream>>>(value2 + (size_t)c * CHUNK * E_DIM, xhi, xlo, XN8);
        proj_kernel<1><<<gproj, 256, 0, stream>>>(xhi, xlo, wvhi, wvlo, bv, gv, betav,
                                                  c * CHUNK, vhi, vlo, nullptr);
    }
    for (int c = 0; c < 2; ++c) {
        split_kernel<<<XN8 / 256, 256, 0, stream>>>(query + (size_t)c * CHUNK * E_DIM, xhi, xlo, XN8);
        proj_kernel<0><<<gproj, 256, 0, stream>>>(xhi, xlo, wqhi, wqlo, bq, gq, betaq,
                                                  c * CHUNK, qsp, nullptr, nullptr);
    }
    for (int c = 0; c < 2; ++c) {
        split_kernel<<<XN8 / 256, 256, 0, stream>>>(key + (size_t)c * CHUNK * E_DIM, xhi, xlo, XN8);
        proj_kernel<0><<<gproj, 256, 0, stream>>>(xhi, xlo, wkhi, wklo, bk, gk, betak,
                                                  c * CHUNK, ksp, nullptr, nullptr);
    }

    attn_kernel<<<dim3(8, 256), 256, 0, stream>>>(qsp, ksp, vhi, vlo, mbits, qsp);

    split_kernel<<<WN8 / 256, 256, 0, stream>>>(Wm, wmhi, wmlo, WN8);
    proj_kernel<2><<<dim3(NTOK / 128, E_DIM / 128), 256, 0, stream>>>(
        qsp, nullptr, wmhi, wmlo, bm, nullptr, nullptr, 0, nullptr, nullptr, out);
}